// Round 1
// baseline (460.428 us; speedup 1.0000x reference)
//
#include <hip/hip_runtime.h>

#define B_ 2
#define S_ 2048
#define D_ 2048
#define H_ 16
#define HD_ 128

typedef unsigned short u16;
typedef __bf16 bf16x8 __attribute__((ext_vector_type(8)));
typedef float f32x4 __attribute__((ext_vector_type(4)));

__device__ __forceinline__ float bf2f(u16 u) {
  unsigned int x = ((unsigned int)u) << 16;
  return __builtin_bit_cast(float, x);
}
__device__ __forceinline__ u16 f2bf(float f) {
  unsigned int u = __builtin_bit_cast(unsigned int, f);
  u += 0x7fffu + ((u >> 16) & 1u);
  return (u16)(u >> 16);
}
__device__ __forceinline__ void async16(const void* g, void* l) {
  __builtin_amdgcn_global_load_lds((const __attribute__((address_space(1))) void*)g,
                                   (__attribute__((address_space(3))) void*)l, 16, 0, 0);
}

// ---------------- elementwise fp32 -> bf16 ----------------
__global__ __launch_bounds__(256) void conv_f32_bf16(const float* __restrict__ in,
                                                     u16* __restrict__ outp, int n) {
  int idx = (blockIdx.x * 256 + threadIdx.x) * 4;
  int stride = gridDim.x * 256 * 4;
  for (; idx < n; idx += stride) {
    float4 v = *(const float4*)(in + idx);
    ushort4 ov = make_ushort4(f2bf(v.x), f2bf(v.y), f2bf(v.z), f2bf(v.w));
    *(ushort4*)(outp + idx) = ov;
  }
}

// ---------------- transpose + convert: in (R,C) fp32 -> out (C,R) bf16 ----------------
__global__ __launch_bounds__(256) void transpose_conv(const float* __restrict__ in,
                                                      u16* __restrict__ outp, int R, int C) {
  __shared__ float tile[32][33];
  int c0 = blockIdx.x * 32, r0 = blockIdx.y * 32;
  int tx = threadIdx.x & 31, ty = threadIdx.x >> 5;
#pragma unroll
  for (int yy = 0; yy < 32; yy += 8)
    tile[ty + yy][tx] = in[(size_t)(r0 + ty + yy) * C + c0 + tx];
  __syncthreads();
#pragma unroll
  for (int yy = 0; yy < 32; yy += 8)
    outp[(size_t)(c0 + ty + yy) * R + r0 + tx] = f2bf(tile[tx][ty + yy]);
}

// ---------------- bf16 per-head transpose: (S,HD) -> (HD,S) ----------------
__global__ __launch_bounds__(256) void transpose_v(const u16* __restrict__ in,
                                                   u16* __restrict__ outp) {
  __shared__ u16 tile[32][33];
  int bhh = blockIdx.z;
  const u16* ip = in + (size_t)bhh * S_ * HD_;
  u16* op = outp + (size_t)bhh * HD_ * S_;
  int hd0 = blockIdx.x * 32, s0 = blockIdx.y * 32;
  int tx = threadIdx.x & 31, ty = threadIdx.x >> 5;
#pragma unroll
  for (int yy = 0; yy < 32; yy += 8)
    tile[ty + yy][tx] = ip[(size_t)(s0 + ty + yy) * HD_ + hd0 + tx];
  __syncthreads();
#pragma unroll
  for (int yy = 0; yy < 32; yy += 8)
    op[(size_t)(hd0 + ty + yy) * S_ + s0 + tx] = tile[tx][ty + yy];
}

// ---------------- RoPE in place on (B,H,S,HD) bf16; blockIdx.y: 0 = Q (scaled), 1 = K ----------------
__global__ __launch_bounds__(256) void rope_kernel(u16* __restrict__ Q, u16* __restrict__ Kk,
                                                   const float* __restrict__ rsin,
                                                   const float* __restrict__ rcos) {
  int t = blockIdx.x * 256 + threadIdx.x;
  u16* base = blockIdx.y ? Kk : Q;
  float scale = blockIdx.y ? 1.0f : 0.08838834764831845f;  // 1/sqrt(128)
  int row = t >> 3, seg = t & 7;
  int s = row & (S_ - 1);
  int i0 = seg * 8;
  u16* p = base + (size_t)row * HD_;
  alignas(16) u16 x1[8], x2[8], o1[8], o2[8];
  *(uint4*)x1 = *(const uint4*)(p + i0);
  *(uint4*)x2 = *(const uint4*)(p + 64 + i0);
  alignas(16) float sn[8], cs[8];
  *(float4*)sn = *(const float4*)(rsin + s * 64 + i0);
  *(float4*)(sn + 4) = *(const float4*)(rsin + s * 64 + i0 + 4);
  *(float4*)cs = *(const float4*)(rcos + s * 64 + i0);
  *(float4*)(cs + 4) = *(const float4*)(rcos + s * 64 + i0 + 4);
#pragma unroll
  for (int j = 0; j < 8; ++j) {
    float a = bf2f(x1[j]), bb = bf2f(x2[j]);
    o1[j] = f2bf((a * cs[j] - bb * sn[j]) * scale);
    o2[j] = f2bf((bb * cs[j] + a * sn[j]) * scale);
  }
  *(uint4*)(p + i0) = *(uint4*)o1;
  *(uint4*)(p + 64 + i0) = *(uint4*)o2;
}

// ---------------- GEMM: C(M,N) = A(M,K) * Bt(N,K)^T, bf16 in, 128x128 tile ----------------
// EPI==0: plain fp32 C.  EPI==1: scatter bf16 into Q/K/V (B,H,S,HD), N-tiles are (h,part).
template <int EPI>
__global__ __launch_bounds__(256) void gemm_bt(const u16* __restrict__ A, const u16* __restrict__ Bt,
                                               float* __restrict__ C, int M, int N, int K,
                                               u16* __restrict__ Qo, u16* __restrict__ Ko,
                                               u16* __restrict__ Vo) {
  __shared__ alignas(16) u16 lsA[128 * 32];
  __shared__ alignas(16) u16 lsB[128 * 32];
  const int tid = threadIdx.x;
  const int lane = tid & 63, wid = tid >> 6;
  const int g = lane >> 4, lr = lane & 15;
  const int wr = wid >> 1, wc = wid & 1;
  const int m0 = blockIdx.y * 128, n0 = blockIdx.x * 128;
  f32x4 acc[4][4] = {};
  const int nk = K >> 5;
  for (int kt = 0; kt < nk; ++kt) {
    const int k0 = kt << 5;
    __syncthreads();
#pragma unroll
    for (int p = 0; p < 2; ++p) {
      const int c = p * 256 + tid;
      const int row = c >> 2;
      const int wb = (c & 3) << 4;
      async16((const char*)(A + (size_t)(m0 + row) * K + k0) + wb, (char*)lsA + c * 16);
      async16((const char*)(Bt + (size_t)(n0 + row) * K + k0) + wb, (char*)lsB + c * 16);
    }
    __syncthreads();
    bf16x8 af[4], bfr[4];
#pragma unroll
    for (int i = 0; i < 4; ++i)
      af[i] = *(const bf16x8*)((const char*)lsA + (wr * 64 + i * 16 + lr) * 64 + g * 16);
#pragma unroll
    for (int j = 0; j < 4; ++j)
      bfr[j] = *(const bf16x8*)((const char*)lsB + (wc * 64 + j * 16 + lr) * 64 + g * 16);
#pragma unroll
    for (int i = 0; i < 4; ++i)
#pragma unroll
      for (int j = 0; j < 4; ++j)
        acc[i][j] = __builtin_amdgcn_mfma_f32_16x16x32_bf16(af[i], bfr[j], acc[i][j], 0, 0, 0);
  }
  if (EPI == 0) {
#pragma unroll
    for (int i = 0; i < 4; ++i)
#pragma unroll
      for (int j = 0; j < 4; ++j)
#pragma unroll
        for (int r = 0; r < 4; ++r) {
          int m = m0 + wr * 64 + i * 16 + 4 * g + r;
          int n = n0 + wc * 64 + j * 16 + lr;
          C[(size_t)m * N + n] = acc[i][j][r];
        }
  } else {
    const int t = blockIdx.x;
    const int part = t % 3, h = t / 3;
    u16* dst = (part == 0) ? Qo : (part == 1 ? Ko : Vo);
#pragma unroll
    for (int i = 0; i < 4; ++i)
#pragma unroll
      for (int j = 0; j < 4; ++j)
#pragma unroll
        for (int r = 0; r < 4; ++r) {
          int m = m0 + wr * 64 + i * 16 + 4 * g + r;
          int hd = wc * 64 + j * 16 + lr;
          int b = m >> 11, s = m & (S_ - 1);
          dst[((size_t)(b * H_ + h) * S_ + s) * HD_ + hd] = f2bf(acc[i][j][r]);
        }
  }
}

// ---------------- flash attention: Q,K (B,H,S,HD) roped (Q pre-scaled), VT (B,H,HD,S) ----------------
// X out: (B,S,H,HD) bf16.  grid = (S/64, B*H), block 256 (4 waves x 16 q-rows).
__global__ __launch_bounds__(256) void attn_fwd(const u16* __restrict__ Q, const u16* __restrict__ K,
                                                const u16* __restrict__ VT, u16* __restrict__ X) {
  const int qt = (int)gridDim.x - 1 - (int)blockIdx.x;  // heavy blocks first
  const int bh = blockIdx.y;
  const int tid = threadIdx.x;
  const int lane = tid & 63, wid = tid >> 6;
  const int g = lane >> 4, lr = lane & 15;

  __shared__ alignas(16) u16 lsK[64 * 128];
  __shared__ alignas(16) u16 lsV[128 * 64];
  __shared__ alignas(16) u16 lsP[4][16 * 72];

  const u16* Qp = Q + (size_t)bh * S_ * HD_;
  const u16* Kp = K + (size_t)bh * S_ * HD_;
  const u16* Vp = VT + (size_t)bh * HD_ * S_;

  const int qrow = qt * 64 + wid * 16 + lr;
  bf16x8 qf[4];
#pragma unroll
  for (int kc = 0; kc < 4; ++kc)
    qf[kc] = *(const bf16x8*)(Qp + (size_t)qrow * HD_ + kc * 32 + g * 8);

  f32x4 o[8] = {};
  float mst[4], lsum[4];
#pragma unroll
  for (int r = 0; r < 4; ++r) { mst[r] = -1e30f; lsum[r] = 0.f; }

  u16* myP = lsP[wid];
  const int qbase = qt * 64 + wid * 16 + 4 * g;

  for (int kt = 0; kt <= qt; ++kt) {
    __syncthreads();  // previous iter done with lsK/lsV/lsP
    // stage K tile [64][128], XOR-swizzled (inverse swizzle on global source)
#pragma unroll
    for (int p = 0; p < 4; ++p) {
      int c = p * 256 + tid;
      int row = c >> 4;
      int w = (c & 15) << 4;
      int wsz = w ^ ((row & 7) << 4);
      async16((const char*)Kp + (((size_t)(kt * 64 + row)) << 8) + wsz, (char*)lsK + c * 16);
    }
    // stage VT tile [128][64], XOR-swizzled
#pragma unroll
    for (int p = 0; p < 4; ++p) {
      int c = p * 256 + tid;
      int row = c >> 3;
      int w = (c & 7) << 4;
      int wsz = w ^ ((row & 7) << 4);
      async16((const char*)Vp + (size_t)row * (S_ * 2) + kt * 128 + wsz, (char*)lsV + c * 16);
    }
    __syncthreads();  // drain global_load_lds
    // QK^T: per wave 16 q-rows x 64 keys
    f32x4 sc[4];
#pragma unroll
    for (int jn = 0; jn < 4; ++jn) {
      f32x4 a = {0.f, 0.f, 0.f, 0.f};
      const int row = jn * 16 + lr;
      const int sw = (row & 7) << 4;
#pragma unroll
      for (int kc = 0; kc < 4; ++kc) {
        int w = (kc * 64 + g * 16) ^ sw;
        bf16x8 kf = *(const bf16x8*)((const char*)lsK + row * 256 + w);
        a = __builtin_amdgcn_mfma_f32_16x16x32_bf16(qf[kc], kf, a, 0, 0, 0);
      }
      sc[jn] = a;
    }
    // softcap + causal mask + online softmax
    float pvv[4][4];
    float rmax[4] = {-1e30f, -1e30f, -1e30f, -1e30f};
#pragma unroll
    for (int jn = 0; jn < 4; ++jn) {
      int key = kt * 64 + jn * 16 + lr;
#pragma unroll
      for (int r = 0; r < 4; ++r) {
        float s = sc[jn][r];
        float z = __expf(-0.04f * s);           // e^{-2*(s/50)}
        float tc = 50.f * (1.f - z) / (1.f + z);  // 50*tanh(s/50)
        if (key > qbase + r) tc = -1e30f;
        pvv[jn][r] = tc;
        rmax[r] = fmaxf(rmax[r], tc);
      }
    }
#pragma unroll
    for (int msk = 1; msk < 16; msk <<= 1)
#pragma unroll
      for (int r = 0; r < 4; ++r) rmax[r] = fmaxf(rmax[r], __shfl_xor(rmax[r], msk, 64));
    float scl[4];
#pragma unroll
    for (int r = 0; r < 4; ++r) {
      float mn = fmaxf(mst[r], rmax[r]);
      scl[r] = __expf(mst[r] - mn);
      mst[r] = mn;
    }
    float rsum[4] = {0.f, 0.f, 0.f, 0.f};
#pragma unroll
    for (int jn = 0; jn < 4; ++jn)
#pragma unroll
      for (int r = 0; r < 4; ++r) {
        float p = __expf(pvv[jn][r] - mst[r]);
        pvv[jn][r] = p;
        rsum[r] += p;
      }
#pragma unroll
    for (int msk = 1; msk < 16; msk <<= 1)
#pragma unroll
      for (int r = 0; r < 4; ++r) rsum[r] += __shfl_xor(rsum[r], msk, 64);
#pragma unroll
    for (int r = 0; r < 4; ++r) lsum[r] = lsum[r] * scl[r] + rsum[r];
#pragma unroll
    for (int jh = 0; jh < 8; ++jh)
#pragma unroll
      for (int r = 0; r < 4; ++r) o[jh][r] *= scl[r];
    // P -> LDS (bf16), re-layout D->A
#pragma unroll
    for (int jn = 0; jn < 4; ++jn)
#pragma unroll
      for (int r = 0; r < 4; ++r)
        myP[(4 * g + r) * 72 + jn * 16 + lr] = f2bf(pvv[jn][r]);
    __syncthreads();
    // PV: o[16 q][128 hd] += P[16][64] * V[64][128]
#pragma unroll
    for (int kc = 0; kc < 2; ++kc) {
      bf16x8 pa = *(const bf16x8*)(myP + lr * 72 + kc * 32 + g * 8);
#pragma unroll
      for (int jh = 0; jh < 8; ++jh) {
        int row = jh * 16 + lr;
        int w = (kc * 64 + g * 16) ^ ((row & 7) << 4);
        bf16x8 vf = *(const bf16x8*)((const char*)lsV + row * 128 + w);
        o[jh] = __builtin_amdgcn_mfma_f32_16x16x32_bf16(pa, vf, o[jh], 0, 0, 0);
      }
    }
  }
  // epilogue: normalize + write X (B,S,H,HD)
  const int b = bh >> 4, h = bh & 15;
#pragma unroll
  for (int r = 0; r < 4; ++r) {
    float inv = 1.f / lsum[r];
    int s = qbase + r;
    u16* xp = X + ((size_t)(b * S_ + s)) * D_ + h * HD_;
#pragma unroll
    for (int jh = 0; jh < 8; ++jh) xp[jh * 16 + lr] = f2bf(o[jh][r] * inv);
  }
}

extern "C" void kernel_launch(void* const* d_in, const int* in_sizes, int n_in,
                              void* d_out, int out_size, void* d_ws, size_t ws_size,
                              hipStream_t stream) {
  const float* inputs = (const float*)d_in[0];
  const float* w_in = (const float*)d_in[1];
  const float* w_out = (const float*)d_in[2];
  const float* rsin = (const float*)d_in[3];
  const float* rcos = (const float*)d_in[4];
  float* out = (float*)d_out;

  char* ws = (char*)d_ws;
  u16* bfA = (u16*)(ws);                   // 16,777,216 B   (B*S, D) bf16
  u16* w_inT = (u16*)(ws + 16777216);      // 25,165,824 B   (6144, 2048) bf16
  u16* Qraw = (u16*)(ws + 41943040);       // 16,777,216 B   (B,H,S,HD)
  u16* Kraw = (u16*)(ws + 58720256);       // 16,777,216 B
  u16* Vraw = (u16*)(ws + 75497472);       // 16,777,216 B
  u16* VT = (u16*)(ws + 92274688);         // 16,777,216 B   (B,H,HD,S)
  u16* Xbuf = (u16*)(ws);                  // reuse bfA region (done after gemm1)
  u16* w_outT = (u16*)(ws + 16777216);     // reuse w_inT region (done after gemm1)

  conv_f32_bf16<<<2048, 256, 0, stream>>>(inputs, bfA, B_ * S_ * D_);
  transpose_conv<<<dim3(6144 / 32, 2048 / 32), 256, 0, stream>>>(w_in, w_inT, 2048, 6144);
  gemm_bt<1><<<dim3(48, 32), 256, 0, stream>>>(bfA, w_inT, nullptr, 4096, 6144, 2048,
                                               Qraw, Kraw, Vraw);
  transpose_conv<<<dim3(2048 / 32, 2048 / 32), 256, 0, stream>>>(w_out, w_outT, 2048, 2048);
  rope_kernel<<<dim3(2048, 2), 256, 0, stream>>>(Qraw, Kraw, rsin, rcos);
  transpose_v<<<dim3(4, 64, 32), 256, 0, stream>>>(Vraw, VT);
  attn_fwd<<<dim3(32, 32), 256, 0, stream>>>(Qraw, Kraw, VT, Xbuf);
  gemm_bt<0><<<dim3(16, 32), 256, 0, stream>>>(Xbuf, w_outT, out, 4096, 2048, 2048,
                                               nullptr, nullptr, nullptr);
}

// Round 2
// 319.524 us; speedup vs baseline: 1.4410x; 1.4410x over previous
//
#include <hip/hip_runtime.h>

#define B_ 2
#define S_ 2048
#define D_ 2048
#define H_ 16
#define HD_ 128
#define NT_ (S_ / 64)

typedef unsigned short u16;
typedef __bf16 bf16x8 __attribute__((ext_vector_type(8)));
typedef float f32x4 __attribute__((ext_vector_type(4)));

__device__ __forceinline__ float bf2f(u16 u) {
  unsigned int x = ((unsigned int)u) << 16;
  return __builtin_bit_cast(float, x);
}
__device__ __forceinline__ u16 f2bf(float f) {
  unsigned int u = __builtin_bit_cast(unsigned int, f);
  u += 0x7fffu + ((u >> 16) & 1u);
  return (u16)(u >> 16);
}
__device__ __forceinline__ void async16(const void* g, void* l) {
  __builtin_amdgcn_global_load_lds((const __attribute__((address_space(1))) void*)g,
                                   (__attribute__((address_space(3))) void*)l, 16, 0, 0);
}
__device__ __forceinline__ float vexp2(float x) {  // 2^x, single v_exp_f32
  float r;
  asm("v_exp_f32 %0, %1" : "=v"(r) : "v"(x));
  return r;
}
__device__ __forceinline__ float vrcp(float x) {  // approx 1/x, single v_rcp_f32
  float r;
  asm("v_rcp_f32 %0, %1" : "=v"(r) : "v"(x));
  return r;
}

// ---------------- elementwise fp32 -> bf16 ----------------
__global__ __launch_bounds__(256) void conv_f32_bf16(const float* __restrict__ in,
                                                     u16* __restrict__ outp, int n) {
  int idx = (blockIdx.x * 256 + threadIdx.x) * 4;
  int stride = gridDim.x * 256 * 4;
  for (; idx < n; idx += stride) {
    float4 v = *(const float4*)(in + idx);
    ushort4 ov = make_ushort4(f2bf(v.x), f2bf(v.y), f2bf(v.z), f2bf(v.w));
    *(ushort4*)(outp + idx) = ov;
  }
}

// ---------------- transpose + convert: in (R,C) fp32 -> out (C,R) bf16 ----------------
__global__ __launch_bounds__(256) void transpose_conv(const float* __restrict__ in,
                                                      u16* __restrict__ outp, int R, int C) {
  __shared__ float tile[32][33];
  int c0 = blockIdx.x * 32, r0 = blockIdx.y * 32;
  int tx = threadIdx.x & 31, ty = threadIdx.x >> 5;
#pragma unroll
  for (int yy = 0; yy < 32; yy += 8)
    tile[ty + yy][tx] = in[(size_t)(r0 + ty + yy) * C + c0 + tx];
  __syncthreads();
#pragma unroll
  for (int yy = 0; yy < 32; yy += 8)
    outp[(size_t)(c0 + ty + yy) * R + r0 + tx] = f2bf(tile[tx][ty + yy]);
}

// ---------------- bf16 per-head transpose: (S,HD) -> (HD,S) ----------------
__global__ __launch_bounds__(256) void transpose_v(const u16* __restrict__ in,
                                                   u16* __restrict__ outp) {
  __shared__ u16 tile[32][33];
  int bhh = blockIdx.z;
  const u16* ip = in + (size_t)bhh * S_ * HD_;
  u16* op = outp + (size_t)bhh * HD_ * S_;
  int hd0 = blockIdx.x * 32, s0 = blockIdx.y * 32;
  int tx = threadIdx.x & 31, ty = threadIdx.x >> 5;
#pragma unroll
  for (int yy = 0; yy < 32; yy += 8)
    tile[ty + yy][tx] = ip[(size_t)(s0 + ty + yy) * HD_ + hd0 + tx];
  __syncthreads();
#pragma unroll
  for (int yy = 0; yy < 32; yy += 8)
    op[(size_t)(hd0 + ty + yy) * S_ + s0 + tx] = tile[tx][ty + yy];
}

// ---------------- RoPE in place on (B,H,S,HD) bf16; blockIdx.y: 0 = Q (scaled), 1 = K ----------------
__global__ __launch_bounds__(256) void rope_kernel(u16* __restrict__ Q, u16* __restrict__ Kk,
                                                   const float* __restrict__ rsin,
                                                   const float* __restrict__ rcos) {
  int t = blockIdx.x * 256 + threadIdx.x;
  u16* base = blockIdx.y ? Kk : Q;
  float scale = blockIdx.y ? 1.0f : 0.08838834764831845f;  // 1/sqrt(128)
  int row = t >> 3, seg = t & 7;
  int s = row & (S_ - 1);
  int i0 = seg * 8;
  u16* p = base + (size_t)row * HD_;
  alignas(16) u16 x1[8], x2[8], o1[8], o2[8];
  *(uint4*)x1 = *(const uint4*)(p + i0);
  *(uint4*)x2 = *(const uint4*)(p + 64 + i0);
  alignas(16) float sn[8], cs[8];
  *(float4*)sn = *(const float4*)(rsin + s * 64 + i0);
  *(float4*)(sn + 4) = *(const float4*)(rsin + s * 64 + i0 + 4);
  *(float4*)cs = *(const float4*)(rcos + s * 64 + i0);
  *(float4*)(cs + 4) = *(const float4*)(rcos + s * 64 + i0 + 4);
#pragma unroll
  for (int j = 0; j < 8; ++j) {
    float a = bf2f(x1[j]), bb = bf2f(x2[j]);
    o1[j] = f2bf((a * cs[j] - bb * sn[j]) * scale);
    o2[j] = f2bf((bb * cs[j] + a * sn[j]) * scale);
  }
  *(uint4*)(p + i0) = *(uint4*)o1;
  *(uint4*)(p + 64 + i0) = *(uint4*)o2;
}

// ---------------- GEMM: C(M,N) = A(M,K) * Bt(N,K)^T, bf16 in, 128x128 tile ----------------
template <int EPI>
__global__ __launch_bounds__(256) void gemm_bt(const u16* __restrict__ A, const u16* __restrict__ Bt,
                                               float* __restrict__ C, int M, int N, int K,
                                               u16* __restrict__ Qo, u16* __restrict__ Ko,
                                               u16* __restrict__ Vo) {
  __shared__ alignas(16) u16 lsA[128 * 32];
  __shared__ alignas(16) u16 lsB[128 * 32];
  const int tid = threadIdx.x;
  const int lane = tid & 63, wid = tid >> 6;
  const int g = lane >> 4, lr = lane & 15;
  const int wr = wid >> 1, wc = wid & 1;
  const int m0 = blockIdx.y * 128, n0 = blockIdx.x * 128;
  f32x4 acc[4][4] = {};
  const int nk = K >> 5;
  for (int kt = 0; kt < nk; ++kt) {
    const int k0 = kt << 5;
    __syncthreads();
#pragma unroll
    for (int p = 0; p < 2; ++p) {
      const int c = p * 256 + tid;
      const int row = c >> 2;
      const int wb = (c & 3) << 4;
      async16((const char*)(A + (size_t)(m0 + row) * K + k0) + wb, (char*)lsA + c * 16);
      async16((const char*)(Bt + (size_t)(n0 + row) * K + k0) + wb, (char*)lsB + c * 16);
    }
    __syncthreads();
    bf16x8 af[4], bfr[4];
#pragma unroll
    for (int i = 0; i < 4; ++i)
      af[i] = *(const bf16x8*)((const char*)lsA + (wr * 64 + i * 16 + lr) * 64 + g * 16);
#pragma unroll
    for (int j = 0; j < 4; ++j)
      bfr[j] = *(const bf16x8*)((const char*)lsB + (wc * 64 + j * 16 + lr) * 64 + g * 16);
#pragma unroll
    for (int i = 0; i < 4; ++i)
#pragma unroll
      for (int j = 0; j < 4; ++j)
        acc[i][j] = __builtin_amdgcn_mfma_f32_16x16x32_bf16(af[i], bfr[j], acc[i][j], 0, 0, 0);
  }
  if (EPI == 0) {
#pragma unroll
    for (int i = 0; i < 4; ++i)
#pragma unroll
      for (int j = 0; j < 4; ++j)
#pragma unroll
        for (int r = 0; r < 4; ++r) {
          int m = m0 + wr * 64 + i * 16 + 4 * g + r;
          int n = n0 + wc * 64 + j * 16 + lr;
          C[(size_t)m * N + n] = acc[i][j][r];
        }
  } else {
    const int t = blockIdx.x;
    const int part = t % 3, h = t / 3;
    u16* dst = (part == 0) ? Qo : (part == 1 ? Ko : Vo);
#pragma unroll
    for (int i = 0; i < 4; ++i)
#pragma unroll
      for (int j = 0; j < 4; ++j)
#pragma unroll
        for (int r = 0; r < 4; ++r) {
          int m = m0 + wr * 64 + i * 16 + 4 * g + r;
          int hd = wc * 64 + j * 16 + lr;
          int b = m >> 11, s = m & (S_ - 1);
          dst[((size_t)(b * H_ + h) * S_ + s) * HD_ + hd] = f2bf(acc[i][j][r]);
        }
  }
}

// ---------------- flash attention, rewritten ----------------
// Q,K (B,H,S,HD) roped (Q pre-scaled), VT (B,H,HD,S). X out: (B,S,H,HD) bf16.
// grid = (NT/2, B*H), block 256 (4 waves x 16 q-rows). Each block does 2 q-tiles
// (qt = NT-1-bx then qt = bx) -> exactly NT+1 = 33 tile-iters per block, uniform.
// Double-buffered K/V staging: issue next tile's global_load_lds before compute,
// single __syncthreads per iteration (its vmcnt(0) drain lands after ~full compute).
// Softmax with FIXED max = 50 (softcap bound): p = exp(tc-50) = 2^(c2 * z/(1+z)),
// z = 2^(c1*s). No running max, no per-tile cross-lane reductions, no o-rescale;
// row-sum accumulated per-lane, reduced once at the end. Safe: causal diagonal
// score is ||q||^2/sqrt(HD) > 0 so row lsum >= e^-50 (f32/bf16-normal).
__global__ __launch_bounds__(256) void attn_fwd(const u16* __restrict__ Q, const u16* __restrict__ K,
                                                const u16* __restrict__ VT, u16* __restrict__ X) {
  const int bx = blockIdx.x;
  const int bh = blockIdx.y;
  const int tid = threadIdx.x;
  const int lane = tid & 63, wid = tid >> 6;
  const int g = lane >> 4, lr = lane & 15;

  __shared__ alignas(16) u16 lsK[2][64 * 128];
  __shared__ alignas(16) u16 lsV[2][128 * 64];
  __shared__ alignas(16) u16 lsP[4][16 * 72];

  const u16* Qp = Q + (size_t)bh * S_ * HD_;
  const u16* Kp = K + (size_t)bh * S_ * HD_;
  const u16* Vp = VT + (size_t)bh * HD_ * S_;
  u16* myP = lsP[wid];
  const int b = bh >> 4, h = bh & 15;

  const float c1 = -0.057707802f;   // -0.04 * log2(e)
  const float c2 = -144.26950409f;  // -100 * log2(e)

#pragma unroll 1
  for (int pass = 0; pass < 2; ++pass) {
    const int qt = pass ? bx : (NT_ - 1 - bx);
    const int qrow = qt * 64 + wid * 16 + lr;
    const int qbase = qt * 64 + wid * 16 + 4 * g;

    bf16x8 qf[4];
#pragma unroll
    for (int kc = 0; kc < 4; ++kc)
      qf[kc] = *(const bf16x8*)(Qp + (size_t)qrow * HD_ + kc * 32 + g * 8);

    f32x4 o[8] = {};
    float psum[4] = {0.f, 0.f, 0.f, 0.f};

    // prologue: stage tile 0 into buffer 0
#pragma unroll
    for (int p = 0; p < 4; ++p) {
      int c = p * 256 + tid;
      int rowk = c >> 4;
      int wsk = ((c & 15) << 4) ^ ((rowk & 7) << 4);
      async16((const char*)Kp + (((size_t)rowk) << 8) + wsk, (char*)lsK[0] + c * 16);
      int rowv = c >> 3;
      int wsv = ((c & 7) << 4) ^ ((rowv & 7) << 4);
      async16((const char*)Vp + (size_t)rowv * (S_ * 2) + wsv, (char*)lsV[0] + c * 16);
    }
    __syncthreads();  // vmcnt(0) drain + barrier

    int cur = 0;
    for (int kt = 0; kt <= qt; ++kt) {
      // issue next tile's stage into the other buffer (overlaps with compute below)
      if (kt < qt) {
        const int nxt = kt + 1;
#pragma unroll
        for (int p = 0; p < 4; ++p) {
          int c = p * 256 + tid;
          int rowk = c >> 4;
          int wsk = ((c & 15) << 4) ^ ((rowk & 7) << 4);
          async16((const char*)Kp + (((size_t)(nxt * 64 + rowk)) << 8) + wsk,
                  (char*)lsK[cur ^ 1] + c * 16);
          int rowv = c >> 3;
          int wsv = ((c & 7) << 4) ^ ((rowv & 7) << 4);
          async16((const char*)Vp + (size_t)rowv * (S_ * 2) + nxt * 128 + wsv,
                  (char*)lsV[cur ^ 1] + c * 16);
        }
      }
      // QK^T: per wave 16 q-rows x 64 keys
      f32x4 sc[4];
#pragma unroll
      for (int jn = 0; jn < 4; ++jn) {
        f32x4 a = {0.f, 0.f, 0.f, 0.f};
        const int row = jn * 16 + lr;
        const int sw = (row & 7) << 4;
#pragma unroll
        for (int kc = 0; kc < 4; ++kc) {
          int w = (kc * 64 + g * 16) ^ sw;
          bf16x8 kf = *(const bf16x8*)((const char*)lsK[cur] + row * 256 + w);
          a = __builtin_amdgcn_mfma_f32_16x16x32_bf16(qf[kc], kf, a, 0, 0, 0);
        }
        sc[jn] = a;
      }
      // softcap + mask + fixed-max softmax; write P tile
#pragma unroll
      for (int jn = 0; jn < 4; ++jn) {
        int key = kt * 64 + jn * 16 + lr;
#pragma unroll
        for (int r = 0; r < 4; ++r) {
          float z = vexp2(c1 * sc[jn][r]);
          float p = vexp2(c2 * z * vrcp(1.f + z));
          if (key > qbase + r) p = 0.f;
          psum[r] += p;
          myP[(4 * g + r) * 72 + jn * 16 + lr] = f2bf(p);
        }
      }
      // PV: o[16 q][128 hd] += P[16][64] * V[64][128]   (same-wave lgkm dep on myP)
#pragma unroll
      for (int kc = 0; kc < 2; ++kc) {
        bf16x8 pa = *(const bf16x8*)(myP + lr * 72 + kc * 32 + g * 8);
#pragma unroll
        for (int jh = 0; jh < 8; ++jh) {
          int row = jh * 16 + lr;
          int w = (kc * 64 + g * 16) ^ ((row & 7) << 4);
          bf16x8 vf = *(const bf16x8*)((const char*)lsV[cur] + row * 128 + w);
          o[jh] = __builtin_amdgcn_mfma_f32_16x16x32_bf16(pa, vf, o[jh], 0, 0, 0);
        }
      }
      __syncthreads();  // all waves done reading cur; staged nxt complete (vmcnt drain)
      cur ^= 1;
    }
    // epilogue: reduce row-sums across the 16-lane lr group, normalize, write X
    float lsum[4];
#pragma unroll
    for (int r = 0; r < 4; ++r) {
      float s = psum[r];
#pragma unroll
      for (int msk = 1; msk < 16; msk <<= 1) s += __shfl_xor(s, msk, 64);
      lsum[r] = s;
    }
#pragma unroll
    for (int r = 0; r < 4; ++r) {
      float inv = 1.f / lsum[r];
      int s = qbase + r;
      u16* xp = X + ((size_t)(b * S_ + s)) * D_ + h * HD_;
#pragma unroll
      for (int jh = 0; jh < 8; ++jh) xp[jh * 16 + lr] = f2bf(o[jh][r] * inv);
    }
  }
}

extern "C" void kernel_launch(void* const* d_in, const int* in_sizes, int n_in,
                              void* d_out, int out_size, void* d_ws, size_t ws_size,
                              hipStream_t stream) {
  const float* inputs = (const float*)d_in[0];
  const float* w_in = (const float*)d_in[1];
  const float* w_out = (const float*)d_in[2];
  const float* rsin = (const float*)d_in[3];
  const float* rcos = (const float*)d_in[4];
  float* out = (float*)d_out;

  char* ws = (char*)d_ws;
  u16* bfA = (u16*)(ws);                   // 16,777,216 B   (B*S, D) bf16
  u16* w_inT = (u16*)(ws + 16777216);      // 25,165,824 B   (6144, 2048) bf16
  u16* Qraw = (u16*)(ws + 41943040);       // 16,777,216 B   (B,H,S,HD)
  u16* Kraw = (u16*)(ws + 58720256);       // 16,777,216 B
  u16* Vraw = (u16*)(ws + 75497472);       // 16,777,216 B
  u16* VT = (u16*)(ws + 92274688);         // 16,777,216 B   (B,H,HD,S)
  u16* Xbuf = (u16*)(ws);                  // reuse bfA region (done after gemm1)
  u16* w_outT = (u16*)(ws + 16777216);     // reuse w_inT region (done after gemm1)

  conv_f32_bf16<<<2048, 256, 0, stream>>>(inputs, bfA, B_ * S_ * D_);
  transpose_conv<<<dim3(6144 / 32, 2048 / 32), 256, 0, stream>>>(w_in, w_inT, 2048, 6144);
  gemm_bt<1><<<dim3(48, 32), 256, 0, stream>>>(bfA, w_inT, nullptr, 4096, 6144, 2048,
                                               Qraw, Kraw, Vraw);
  transpose_conv<<<dim3(2048 / 32, 2048 / 32), 256, 0, stream>>>(w_out, w_outT, 2048, 2048);
  rope_kernel<<<dim3(2048, 2), 256, 0, stream>>>(Qraw, Kraw, rsin, rcos);
  transpose_v<<<dim3(4, 64, 32), 256, 0, stream>>>(Vraw, VT);
  attn_fwd<<<dim3(NT_ / 2, 32), 256, 0, stream>>>(Qraw, Kraw, VT, Xbuf);
  gemm_bt<0><<<dim3(16, 32), 256, 0, stream>>>(Xbuf, w_outT, out, 4096, 2048, 2048,
                                               nullptr, nullptr, nullptr);
}

// Round 3
// 310.278 us; speedup vs baseline: 1.4839x; 1.0298x over previous
//
#include <hip/hip_runtime.h>

#define B_ 2
#define S_ 2048
#define D_ 2048
#define H_ 16
#define HD_ 128
#define NT_ (S_ / 64)
#define NBUF 6

typedef unsigned short u16;
typedef __bf16 bf16x8 __attribute__((ext_vector_type(8)));
typedef float f32x4 __attribute__((ext_vector_type(4)));

__device__ __forceinline__ float bf2f(u16 u) {
  unsigned int x = ((unsigned int)u) << 16;
  return __builtin_bit_cast(float, x);
}
__device__ __forceinline__ u16 f2bf(float f) {
  unsigned int u = __builtin_bit_cast(unsigned int, f);
  u += 0x7fffu + ((u >> 16) & 1u);
  return (u16)(u >> 16);
}
__device__ __forceinline__ void async16(const void* g, void* l) {
  __builtin_amdgcn_global_load_lds((const __attribute__((address_space(1))) void*)g,
                                   (__attribute__((address_space(3))) void*)l, 16, 0, 0);
}
__device__ __forceinline__ float vexp2(float x) {
  float r;
  asm("v_exp_f32 %0, %1" : "=v"(r) : "v"(x));
  return r;
}
__device__ __forceinline__ float vrcp(float x) {
  float r;
  asm("v_rcp_f32 %0, %1" : "=v"(r) : "v"(x));
  return r;
}

// ---------------- elementwise fp32 -> bf16 ----------------
__global__ __launch_bounds__(256) void conv_f32_bf16(const float* __restrict__ in,
                                                     u16* __restrict__ outp, int n) {
  int idx = (blockIdx.x * 256 + threadIdx.x) * 4;
  int stride = gridDim.x * 256 * 4;
  for (; idx < n; idx += stride) {
    float4 v = *(const float4*)(in + idx);
    ushort4 ov = make_ushort4(f2bf(v.x), f2bf(v.y), f2bf(v.z), f2bf(v.w));
    *(ushort4*)(outp + idx) = ov;
  }
}

// ---------------- transpose + convert: in (R,C) fp32 -> out (C,R) bf16 ----------------
__global__ __launch_bounds__(256) void transpose_conv(const float* __restrict__ in,
                                                      u16* __restrict__ outp, int R, int C) {
  __shared__ float tile[32][33];
  int c0 = blockIdx.x * 32, r0 = blockIdx.y * 32;
  int tx = threadIdx.x & 31, ty = threadIdx.x >> 5;
#pragma unroll
  for (int yy = 0; yy < 32; yy += 8)
    tile[ty + yy][tx] = in[(size_t)(r0 + ty + yy) * C + c0 + tx];
  __syncthreads();
#pragma unroll
  for (int yy = 0; yy < 32; yy += 8)
    outp[(size_t)(c0 + ty + yy) * R + r0 + tx] = f2bf(tile[tx][ty + yy]);
}

// ---------------- bf16 per-head transpose: (S,HD) -> (HD,S) ----------------
__global__ __launch_bounds__(256) void transpose_v(const u16* __restrict__ in,
                                                   u16* __restrict__ outp) {
  __shared__ u16 tile[32][33];
  int bhh = blockIdx.z;
  const u16* ip = in + (size_t)bhh * S_ * HD_;
  u16* op = outp + (size_t)bhh * HD_ * S_;
  int hd0 = blockIdx.x * 32, s0 = blockIdx.y * 32;
  int tx = threadIdx.x & 31, ty = threadIdx.x >> 5;
#pragma unroll
  for (int yy = 0; yy < 32; yy += 8)
    tile[ty + yy][tx] = ip[(size_t)(s0 + ty + yy) * HD_ + hd0 + tx];
  __syncthreads();
#pragma unroll
  for (int yy = 0; yy < 32; yy += 8)
    op[(size_t)(hd0 + ty + yy) * S_ + s0 + tx] = tile[tx][ty + yy];
}

// ---------------- RoPE in place on (B,H,S,HD) bf16; blockIdx.y: 0 = Q (scaled), 1 = K ----------------
__global__ __launch_bounds__(256) void rope_kernel(u16* __restrict__ Q, u16* __restrict__ Kk,
                                                   const float* __restrict__ rsin,
                                                   const float* __restrict__ rcos) {
  int t = blockIdx.x * 256 + threadIdx.x;
  u16* base = blockIdx.y ? Kk : Q;
  float scale = blockIdx.y ? 1.0f : 0.08838834764831845f;  // 1/sqrt(128)
  int row = t >> 3, seg = t & 7;
  int s = row & (S_ - 1);
  int i0 = seg * 8;
  u16* p = base + (size_t)row * HD_;
  alignas(16) u16 x1[8], x2[8], o1[8], o2[8];
  *(uint4*)x1 = *(const uint4*)(p + i0);
  *(uint4*)x2 = *(const uint4*)(p + 64 + i0);
  alignas(16) float sn[8], cs[8];
  *(float4*)sn = *(const float4*)(rsin + s * 64 + i0);
  *(float4*)(sn + 4) = *(const float4*)(rsin + s * 64 + i0 + 4);
  *(float4*)cs = *(const float4*)(rcos + s * 64 + i0);
  *(float4*)(cs + 4) = *(const float4*)(rcos + s * 64 + i0 + 4);
#pragma unroll
  for (int j = 0; j < 8; ++j) {
    float a = bf2f(x1[j]), bb = bf2f(x2[j]);
    o1[j] = f2bf((a * cs[j] - bb * sn[j]) * scale);
    o2[j] = f2bf((bb * cs[j] + a * sn[j]) * scale);
  }
  *(uint4*)(p + i0) = *(uint4*)o1;
  *(uint4*)(p + 64 + i0) = *(uint4*)o2;
}

// ---------------- deep-pipelined GEMM: C(M,N) = A(M,K) * Bt(N,K)^T ----------------
// BM=256, BN=128, BK=32. 8 waves (4M x 2N), per-wave 64x64 output, 16 MFMA/phase.
// 6-deep LDS ring (144 KB), counted vmcnt(12) (4 phases x 3 loads in flight),
// raw s_barrier, setprio around MFMA cluster, k-slot XOR swizzle (T2, both sides),
// bijective XCD swizzle (grid % 8 == 0). EPI==0: fp32 C. EPI==1: scatter bf16 QKV.
template <int EPI>
__global__ __launch_bounds__(512, 1) void gemm8p(const u16* __restrict__ A,
                                                 const u16* __restrict__ Bt,
                                                 float* __restrict__ C, int K, int N, int gx,
                                                 u16* __restrict__ Qo, u16* __restrict__ Ko,
                                                 u16* __restrict__ Vo) {
  __shared__ alignas(16) u16 lsA[NBUF][256 * 32];
  __shared__ alignas(16) u16 lsB[NBUF][128 * 32];
  const int tid = threadIdx.x;
  const int lane = tid & 63;
  const int wid = tid >> 6;
  const int g = lane >> 4, lr = lane & 15;
  const int wm = wid >> 1, wn = wid & 1;

  // XCD-aware block swizzle (nwg % 8 == 0 for both call sites)
  const int nwg = gx << 4;
  const int bid = blockIdx.x;
  const int swz = (bid & 7) * (nwg >> 3) + (bid >> 3);
  const int m_idx = swz & 15, n_idx = swz >> 4;  // M/256 == 16 for both GEMMs
  const size_t m0 = (size_t)m_idx * 256, n0 = (size_t)n_idx * 128;

  // staging source pointers (pre-swizzled k-slot so linear LDS dest = swizzled layout)
  const int la0 = tid, la1 = 512 + tid;
  const int rowA0 = la0 >> 2, slA0 = la0 & 3;
  const int rowA1 = la1 >> 2, slA1 = la1 & 3;
  const int rowB = tid >> 2, slB = tid & 3;
  const u16* srcA0 = A + (m0 + rowA0) * K + ((slA0 ^ ((rowA0 >> 1) & 3)) << 3);
  const u16* srcA1 = A + (m0 + rowA1) * K + ((slA1 ^ ((rowA1 >> 1) & 3)) << 3);
  const u16* srcB = Bt + (n0 + rowB) * K + ((slB ^ ((rowB >> 1) & 3)) << 3);

#define STAGE(t, bufi)                                          \
  {                                                             \
    const int koff = (t) << 5;                                  \
    async16(srcA0 + koff, (char*)lsA[bufi] + la0 * 16);         \
    async16(srcA1 + koff, (char*)lsA[bufi] + la1 * 16);         \
    async16(srcB + koff, (char*)lsB[bufi] + tid * 16);          \
  }

  // ds_read byte offsets (swizzled), constant per thread
  int ofsA[4], ofsB[4];
#pragma unroll
  for (int i = 0; i < 4; ++i) {
    int ra = wm * 64 + i * 16 + lr;
    ofsA[i] = ra * 64 + ((g ^ ((ra >> 1) & 3)) << 4);
    int rb = wn * 64 + i * 16 + lr;
    ofsB[i] = rb * 64 + ((g ^ ((rb >> 1) & 3)) << 4);
  }

  f32x4 acc[4][4] = {};
  const int nk = K >> 5;

  // prologue: stage tiles 0..NBUF-2 into bufs 0..NBUF-2
#pragma unroll
  for (int t = 0; t < NBUF - 1; ++t) STAGE(t, t);
  asm volatile("s_waitcnt vmcnt(12)" ::: "memory");  // tile 0 resident
  __builtin_amdgcn_s_barrier();

  int buf = 0;
#pragma unroll 1
  for (int kt = 0; kt < nk; ++kt) {
    bf16x8 af[4], bfr[4];
#pragma unroll
    for (int i = 0; i < 4; ++i) af[i] = *(const bf16x8*)((const char*)lsA[buf] + ofsA[i]);
#pragma unroll
    for (int j = 0; j < 4; ++j) bfr[j] = *(const bf16x8*)((const char*)lsB[buf] + ofsB[j]);
    // stage tile kt+5 into buf-1 (mod 6): that buffer's reads drained before the
    // previous phase's end-barrier, so an early-landing write cannot race them.
    const int st = kt + NBUF - 1;
    const int sbuf = buf == 0 ? NBUF - 1 : buf - 1;
    if (st < nk) STAGE(st, sbuf);
    __builtin_amdgcn_s_barrier();
    __builtin_amdgcn_s_setprio(1);
#pragma unroll
    for (int i = 0; i < 4; ++i)
#pragma unroll
      for (int j = 0; j < 4; ++j)
        acc[i][j] = __builtin_amdgcn_mfma_f32_16x16x32_bf16(af[i], bfr[j], acc[i][j], 0, 0, 0);
    __builtin_amdgcn_s_setprio(0);
    // counted drain: tile kt+1 (staged 4 phases ago) resident; 4 newest stages stay in flight
    asm volatile("s_waitcnt vmcnt(12)" ::: "memory");
    __builtin_amdgcn_s_barrier();
    buf = buf == NBUF - 1 ? 0 : buf + 1;
  }
#undef STAGE

  if (EPI == 0) {
#pragma unroll
    for (int i = 0; i < 4; ++i)
#pragma unroll
      for (int j = 0; j < 4; ++j)
#pragma unroll
        for (int r = 0; r < 4; ++r) {
          size_t m = m0 + wm * 64 + i * 16 + 4 * g + r;
          size_t n = n0 + wn * 64 + j * 16 + lr;
          C[m * N + n] = acc[i][j][r];
        }
  } else {
    const int part = n_idx % 3, h = n_idx / 3;
    u16* dst = (part == 0) ? Qo : (part == 1 ? Ko : Vo);
#pragma unroll
    for (int i = 0; i < 4; ++i)
#pragma unroll
      for (int j = 0; j < 4; ++j)
#pragma unroll
        for (int r = 0; r < 4; ++r) {
          int m = (int)m0 + wm * 64 + i * 16 + 4 * g + r;
          int hd = wn * 64 + j * 16 + lr;
          int b = m >> 11, s = m & (S_ - 1);
          dst[((size_t)(b * H_ + h) * S_ + s) * HD_ + hd] = f2bf(acc[i][j][r]);
        }
  }
}

// ---------------- flash attention (unchanged from R2) ----------------
__global__ __launch_bounds__(256) void attn_fwd(const u16* __restrict__ Q, const u16* __restrict__ K,
                                                const u16* __restrict__ VT, u16* __restrict__ X) {
  const int bx = blockIdx.x;
  const int bh = blockIdx.y;
  const int tid = threadIdx.x;
  const int lane = tid & 63, wid = tid >> 6;
  const int g = lane >> 4, lr = lane & 15;

  __shared__ alignas(16) u16 lsK[2][64 * 128];
  __shared__ alignas(16) u16 lsV[2][128 * 64];
  __shared__ alignas(16) u16 lsP[4][16 * 72];

  const u16* Qp = Q + (size_t)bh * S_ * HD_;
  const u16* Kp = K + (size_t)bh * S_ * HD_;
  const u16* Vp = VT + (size_t)bh * HD_ * S_;
  u16* myP = lsP[wid];
  const int b = bh >> 4, h = bh & 15;

  const float c1 = -0.057707802f;   // -0.04 * log2(e)
  const float c2 = -144.26950409f;  // -100 * log2(e)

#pragma unroll 1
  for (int pass = 0; pass < 2; ++pass) {
    const int qt = pass ? bx : (NT_ - 1 - bx);
    const int qrow = qt * 64 + wid * 16 + lr;
    const int qbase = qt * 64 + wid * 16 + 4 * g;

    bf16x8 qf[4];
#pragma unroll
    for (int kc = 0; kc < 4; ++kc)
      qf[kc] = *(const bf16x8*)(Qp + (size_t)qrow * HD_ + kc * 32 + g * 8);

    f32x4 o[8] = {};
    float psum[4] = {0.f, 0.f, 0.f, 0.f};

#pragma unroll
    for (int p = 0; p < 4; ++p) {
      int c = p * 256 + tid;
      int rowk = c >> 4;
      int wsk = ((c & 15) << 4) ^ ((rowk & 7) << 4);
      async16((const char*)Kp + (((size_t)rowk) << 8) + wsk, (char*)lsK[0] + c * 16);
      int rowv = c >> 3;
      int wsv = ((c & 7) << 4) ^ ((rowv & 7) << 4);
      async16((const char*)Vp + (size_t)rowv * (S_ * 2) + wsv, (char*)lsV[0] + c * 16);
    }
    __syncthreads();

    int cur = 0;
    for (int kt = 0; kt <= qt; ++kt) {
      if (kt < qt) {
        const int nxt = kt + 1;
#pragma unroll
        for (int p = 0; p < 4; ++p) {
          int c = p * 256 + tid;
          int rowk = c >> 4;
          int wsk = ((c & 15) << 4) ^ ((rowk & 7) << 4);
          async16((const char*)Kp + (((size_t)(nxt * 64 + rowk)) << 8) + wsk,
                  (char*)lsK[cur ^ 1] + c * 16);
          int rowv = c >> 3;
          int wsv = ((c & 7) << 4) ^ ((rowv & 7) << 4);
          async16((const char*)Vp + (size_t)rowv * (S_ * 2) + nxt * 128 + wsv,
                  (char*)lsV[cur ^ 1] + c * 16);
        }
      }
      f32x4 sc[4];
#pragma unroll
      for (int jn = 0; jn < 4; ++jn) {
        f32x4 a = {0.f, 0.f, 0.f, 0.f};
        const int row = jn * 16 + lr;
        const int sw = (row & 7) << 4;
#pragma unroll
        for (int kc = 0; kc < 4; ++kc) {
          int w = (kc * 64 + g * 16) ^ sw;
          bf16x8 kf = *(const bf16x8*)((const char*)lsK[cur] + row * 256 + w);
          a = __builtin_amdgcn_mfma_f32_16x16x32_bf16(qf[kc], kf, a, 0, 0, 0);
        }
        sc[jn] = a;
      }
#pragma unroll
      for (int jn = 0; jn < 4; ++jn) {
        int key = kt * 64 + jn * 16 + lr;
#pragma unroll
        for (int r = 0; r < 4; ++r) {
          float z = vexp2(c1 * sc[jn][r]);
          float p = vexp2(c2 * z * vrcp(1.f + z));
          if (key > qbase + r) p = 0.f;
          psum[r] += p;
          myP[(4 * g + r) * 72 + jn * 16 + lr] = f2bf(p);
        }
      }
#pragma unroll
      for (int kc = 0; kc < 2; ++kc) {
        bf16x8 pa = *(const bf16x8*)(myP + lr * 72 + kc * 32 + g * 8);
#pragma unroll
        for (int jh = 0; jh < 8; ++jh) {
          int row = jh * 16 + lr;
          int w = (kc * 64 + g * 16) ^ ((row & 7) << 4);
          bf16x8 vf = *(const bf16x8*)((const char*)lsV[cur] + row * 128 + w);
          o[jh] = __builtin_amdgcn_mfma_f32_16x16x32_bf16(pa, vf, o[jh], 0, 0, 0);
        }
      }
      __syncthreads();
      cur ^= 1;
    }
    float lsum[4];
#pragma unroll
    for (int r = 0; r < 4; ++r) {
      float s = psum[r];
#pragma unroll
      for (int msk = 1; msk < 16; msk <<= 1) s += __shfl_xor(s, msk, 64);
      lsum[r] = s;
    }
#pragma unroll
    for (int r = 0; r < 4; ++r) {
      float inv = 1.f / lsum[r];
      int s = qbase + r;
      u16* xp = X + ((size_t)(b * S_ + s)) * D_ + h * HD_;
#pragma unroll
      for (int jh = 0; jh < 8; ++jh) xp[jh * 16 + lr] = f2bf(o[jh][r] * inv);
    }
  }
}

extern "C" void kernel_launch(void* const* d_in, const int* in_sizes, int n_in,
                              void* d_out, int out_size, void* d_ws, size_t ws_size,
                              hipStream_t stream) {
  const float* inputs = (const float*)d_in[0];
  const float* w_in = (const float*)d_in[1];
  const float* w_out = (const float*)d_in[2];
  const float* rsin = (const float*)d_in[3];
  const float* rcos = (const float*)d_in[4];
  float* out = (float*)d_out;

  char* ws = (char*)d_ws;
  u16* bfA = (u16*)(ws);                   // (B*S, D) bf16
  u16* w_inT = (u16*)(ws + 16777216);      // (6144, 2048) bf16
  u16* Qraw = (u16*)(ws + 41943040);       // (B,H,S,HD)
  u16* Kraw = (u16*)(ws + 58720256);
  u16* Vraw = (u16*)(ws + 75497472);
  u16* VT = (u16*)(ws + 92274688);         // (B,H,HD,S)
  u16* Xbuf = (u16*)(ws);                  // reuse bfA region
  u16* w_outT = (u16*)(ws + 16777216);     // reuse w_inT region

  conv_f32_bf16<<<2048, 256, 0, stream>>>(inputs, bfA, B_ * S_ * D_);
  transpose_conv<<<dim3(6144 / 32, 2048 / 32), 256, 0, stream>>>(w_in, w_inT, 2048, 6144);
  gemm8p<1><<<768, 512, 0, stream>>>(bfA, w_inT, nullptr, 2048, 6144, 48, Qraw, Kraw, Vraw);
  transpose_conv<<<dim3(2048 / 32, 2048 / 32), 256, 0, stream>>>(w_out, w_outT, 2048, 2048);
  rope_kernel<<<dim3(2048, 2), 256, 0, stream>>>(Qraw, Kraw, rsin, rcos);
  transpose_v<<<dim3(4, 64, 32), 256, 0, stream>>>(Vraw, VT);
  attn_fwd<<<dim3(NT_ / 2, 32), 256, 0, stream>>>(Qraw, Kraw, VT, Xbuf);
  gemm8p<0><<<256, 512, 0, stream>>>(Xbuf, w_outT, out, 2048, 2048, 16,
                                     nullptr, nullptr, nullptr);
}

// Round 4
// 299.415 us; speedup vs baseline: 1.5378x; 1.0363x over previous
//
#include <hip/hip_runtime.h>

#define B_ 2
#define S_ 2048
#define D_ 2048
#define H_ 16
#define HD_ 128
#define NT_ (S_ / 64)
#define NBUF 6

typedef unsigned short u16;
typedef __bf16 bf16x8 __attribute__((ext_vector_type(8)));
typedef float f32x4 __attribute__((ext_vector_type(4)));

__device__ __forceinline__ float bf2f(u16 u) {
  unsigned int x = ((unsigned int)u) << 16;
  return __builtin_bit_cast(float, x);
}
__device__ __forceinline__ u16 f2bf(float f) {
  unsigned int u = __builtin_bit_cast(unsigned int, f);
  u += 0x7fffu + ((u >> 16) & 1u);
  return (u16)(u >> 16);
}
__device__ __forceinline__ void async16(const void* g, void* l) {
  __builtin_amdgcn_global_load_lds((const __attribute__((address_space(1))) void*)g,
                                   (__attribute__((address_space(3))) void*)l, 16, 0, 0);
}
__device__ __forceinline__ float vexp2(float x) {
  float r;
  asm("v_exp_f32 %0, %1" : "=v"(r) : "v"(x));
  return r;
}
__device__ __forceinline__ float vrcp(float x) {
  float r;
  asm("v_rcp_f32 %0, %1" : "=v"(r) : "v"(x));
  return r;
}

// ---------------- elementwise fp32 -> bf16 ----------------
__global__ __launch_bounds__(256) void conv_f32_bf16(const float* __restrict__ in,
                                                     u16* __restrict__ outp, int n) {
  int idx = (blockIdx.x * 256 + threadIdx.x) * 4;
  int stride = gridDim.x * 256 * 4;
  for (; idx < n; idx += stride) {
    float4 v = *(const float4*)(in + idx);
    ushort4 ov = make_ushort4(f2bf(v.x), f2bf(v.y), f2bf(v.z), f2bf(v.w));
    *(ushort4*)(outp + idx) = ov;
  }
}

// ---------------- transpose + convert: in (R,C) fp32 -> out (C,R) bf16 ----------------
__global__ __launch_bounds__(256) void transpose_conv(const float* __restrict__ in,
                                                      u16* __restrict__ outp, int R, int C) {
  __shared__ float tile[32][33];
  int c0 = blockIdx.x * 32, r0 = blockIdx.y * 32;
  int tx = threadIdx.x & 31, ty = threadIdx.x >> 5;
#pragma unroll
  for (int yy = 0; yy < 32; yy += 8)
    tile[ty + yy][tx] = in[(size_t)(r0 + ty + yy) * C + c0 + tx];
  __syncthreads();
#pragma unroll
  for (int yy = 0; yy < 32; yy += 8)
    outp[(size_t)(c0 + ty + yy) * R + r0 + tx] = f2bf(tile[tx][ty + yy]);
}

// ---------------- bf16 per-head transpose: (S,HD) -> (HD,S) ----------------
__global__ __launch_bounds__(256) void transpose_v(const u16* __restrict__ in,
                                                   u16* __restrict__ outp) {
  __shared__ u16 tile[32][33];
  int bhh = blockIdx.z;
  const u16* ip = in + (size_t)bhh * S_ * HD_;
  u16* op = outp + (size_t)bhh * HD_ * S_;
  int hd0 = blockIdx.x * 32, s0 = blockIdx.y * 32;
  int tx = threadIdx.x & 31, ty = threadIdx.x >> 5;
#pragma unroll
  for (int yy = 0; yy < 32; yy += 8)
    tile[ty + yy][tx] = ip[(size_t)(s0 + ty + yy) * HD_ + hd0 + tx];
  __syncthreads();
#pragma unroll
  for (int yy = 0; yy < 32; yy += 8)
    op[(size_t)(hd0 + ty + yy) * S_ + s0 + tx] = tile[tx][ty + yy];
}

// ---------------- RoPE in place on (B,H,S,HD) bf16; blockIdx.y: 0 = Q (scaled), 1 = K ----------------
__global__ __launch_bounds__(256) void rope_kernel(u16* __restrict__ Q, u16* __restrict__ Kk,
                                                   const float* __restrict__ rsin,
                                                   const float* __restrict__ rcos) {
  int t = blockIdx.x * 256 + threadIdx.x;
  u16* base = blockIdx.y ? Kk : Q;
  float scale = blockIdx.y ? 1.0f : 0.08838834764831845f;  // 1/sqrt(128)
  int row = t >> 3, seg = t & 7;
  int s = row & (S_ - 1);
  int i0 = seg * 8;
  u16* p = base + (size_t)row * HD_;
  alignas(16) u16 x1[8], x2[8], o1[8], o2[8];
  *(uint4*)x1 = *(const uint4*)(p + i0);
  *(uint4*)x2 = *(const uint4*)(p + 64 + i0);
  alignas(16) float sn[8], cs[8];
  *(float4*)sn = *(const float4*)(rsin + s * 64 + i0);
  *(float4*)(sn + 4) = *(const float4*)(rsin + s * 64 + i0 + 4);
  *(float4*)cs = *(const float4*)(rcos + s * 64 + i0);
  *(float4*)(cs + 4) = *(const float4*)(rcos + s * 64 + i0 + 4);
#pragma unroll
  for (int j = 0; j < 8; ++j) {
    float a = bf2f(x1[j]), bb = bf2f(x2[j]);
    o1[j] = f2bf((a * cs[j] - bb * sn[j]) * scale);
    o2[j] = f2bf((bb * cs[j] + a * sn[j]) * scale);
  }
  *(uint4*)(p + i0) = *(uint4*)o1;
  *(uint4*)(p + 64 + i0) = *(uint4*)o2;
}

// ---------------- 256x256 deep-pipelined GEMM: C = A(M,K) * Bt(N,K)^T ----------------
// 8 waves (2M x 4N), per-wave 128x64 out (32 MFMA / K32-step, acc=128 VGPR).
// BK=32, 4-deep LDS ring (128 KB), 2 sub-phases per K-step (16 MFMA each; A-frags
// register-reused across both). Counted vmcnt(8): tiles kt+2, kt+3 in flight.
// EPI==1: scatter bf16 QKV. EPI==0: plain fp32 C.
template <int EPI>
__global__ __launch_bounds__(512, 2) void gemm256(const u16* __restrict__ A,
                                                  const u16* __restrict__ Bt,
                                                  float* __restrict__ C, int K, int N, int nchunk,
                                                  u16* __restrict__ Qo, u16* __restrict__ Ko,
                                                  u16* __restrict__ Vo) {
  __shared__ alignas(16) u16 lsA[4][256 * 32];
  __shared__ alignas(16) u16 lsB[4][256 * 32];
  const int tid = threadIdx.x;
  const int lane = tid & 63;
  const int wid = tid >> 6;
  const int g = lane >> 4, lr = lane & 15;
  const int wm = wid >> 2, wn = wid & 3;  // 2M x 4N

  // bijective XCD swizzle (grid % 8 == 0 at both call sites)
  const int nwg = nchunk << 4;  // M/256 == 16 always
  const int bid = blockIdx.x;
  const int swz = (bid & 7) * (nwg >> 3) + (bid >> 3);
  const int m_idx = swz & 15, n_idx = swz >> 4;
  const size_t m0 = (size_t)m_idx * 256, n0 = (size_t)n_idx * 256;

  // staging sources (pre-swizzled k-slot so linear LDS dest == swizzled layout)
  const u16* sA[2];
  const u16* sB[2];
  int dst16[2];
#pragma unroll
  for (int r = 0; r < 2; ++r) {
    int idx = r * 512 + tid;
    int row = idx >> 2, sl = idx & 3;
    int slot = sl ^ ((row >> 1) & 3);
    sA[r] = A + (m0 + row) * K + (slot << 3);
    sB[r] = Bt + (n0 + row) * K + (slot << 3);
    dst16[r] = idx * 16;
  }
#define STA(t, bufi)                                            \
  {                                                             \
    async16(sA[0] + ((t) << 5), (char*)lsA[bufi] + dst16[0]);   \
    async16(sA[1] + ((t) << 5), (char*)lsA[bufi] + dst16[1]);   \
  }
#define STB(t, bufi)                                            \
  {                                                             \
    async16(sB[0] + ((t) << 5), (char*)lsB[bufi] + dst16[0]);   \
    async16(sB[1] + ((t) << 5), (char*)lsB[bufi] + dst16[1]);   \
  }

  // swizzled ds_read byte offsets (constant per thread)
  int ofsA[8], ofsB[4];
#pragma unroll
  for (int i = 0; i < 8; ++i) {
    int ra = wm * 128 + i * 16 + lr;
    ofsA[i] = ra * 64 + ((g ^ ((ra >> 1) & 3)) << 4);
  }
#pragma unroll
  for (int j = 0; j < 4; ++j) {
    int rb = wn * 64 + j * 16 + lr;
    ofsB[j] = rb * 64 + ((g ^ ((rb >> 1) & 3)) << 4);
  }

  f32x4 acc[8][4] = {};
  const int nk = K >> 5;

  // prologue: stage tiles 0..2 into bufs 0..2 (12 loads); drain to tile 0 (8 left)
#pragma unroll
  for (int t = 0; t < 3; ++t) {
    STA(t, t);
    STB(t, t);
  }
  asm volatile("s_waitcnt vmcnt(8)" ::: "memory");
  __builtin_amdgcn_s_barrier();

#pragma unroll 1
  for (int kt = 0; kt < nk; ++kt) {
    const int buf = kt & 3;
    const int st = kt + 3;
    const int sb = st & 3;
    // ---- sub-phase 1: read A0..7 + B0..1, stage next A; MFMA n-half 0
    bf16x8 af[8], bf01[2];
#pragma unroll
    for (int i = 0; i < 8; ++i) af[i] = *(const bf16x8*)((const char*)lsA[buf] + ofsA[i]);
#pragma unroll
    for (int j = 0; j < 2; ++j) bf01[j] = *(const bf16x8*)((const char*)lsB[buf] + ofsB[j]);
    if (st < nk) STA(st, sb);
    __builtin_amdgcn_s_barrier();
    __builtin_amdgcn_s_setprio(1);
#pragma unroll
    for (int i = 0; i < 8; ++i)
#pragma unroll
      for (int j = 0; j < 2; ++j)
        acc[i][j] = __builtin_amdgcn_mfma_f32_16x16x32_bf16(af[i], bf01[j], acc[i][j], 0, 0, 0);
    __builtin_amdgcn_s_setprio(0);
    // ---- sub-phase 2: read B2..3, stage next B; MFMA n-half 1 (A reused from regs)
    bf16x8 bf23[2];
#pragma unroll
    for (int j = 0; j < 2; ++j) bf23[j] = *(const bf16x8*)((const char*)lsB[buf] + ofsB[2 + j]);
    if (st < nk) STB(st, sb);
    __builtin_amdgcn_s_barrier();
    __builtin_amdgcn_s_setprio(1);
#pragma unroll
    for (int i = 0; i < 8; ++i)
#pragma unroll
      for (int j = 0; j < 2; ++j)
        acc[i][2 + j] =
            __builtin_amdgcn_mfma_f32_16x16x32_bf16(af[i], bf23[j], acc[i][2 + j], 0, 0, 0);
    __builtin_amdgcn_s_setprio(0);
    // counted drain: tile kt+1 resident; tiles kt+2, kt+3 (8 loads) stay in flight
    asm volatile("s_waitcnt vmcnt(8)" ::: "memory");
    __builtin_amdgcn_s_barrier();
  }
#undef STA
#undef STB

  if (EPI == 0) {
#pragma unroll
    for (int i = 0; i < 8; ++i)
#pragma unroll
      for (int j = 0; j < 4; ++j)
#pragma unroll
        for (int r = 0; r < 4; ++r) {
          size_t m = m0 + wm * 128 + i * 16 + 4 * g + r;
          size_t n = n0 + wn * 64 + j * 16 + lr;
          C[m * N + n] = acc[i][j][r];
        }
  } else {
    // N-chunk (128 cols) -> (h, part); chunk index is wave-uniform
    const int c = (int)(n0 >> 7) + (wn >> 1);
    const int h = c / 3, part = c % 3;
    u16* dst = (part == 0) ? Qo : (part == 1 ? Ko : Vo);
#pragma unroll
    for (int i = 0; i < 8; ++i)
#pragma unroll
      for (int j = 0; j < 4; ++j)
#pragma unroll
        for (int r = 0; r < 4; ++r) {
          int m = (int)m0 + wm * 128 + i * 16 + 4 * g + r;
          int hd = (wn & 1) * 64 + j * 16 + lr;
          int b = m >> 11, s = m & (S_ - 1);
          dst[((size_t)(b * H_ + h) * S_ + s) * HD_ + hd] = f2bf(acc[i][j][r]);
        }
  }
}

// ---------------- R3 deep-pipelined 256x128 GEMM (kept for gemm2, control) ----------------
template <int EPI>
__global__ __launch_bounds__(512, 1) void gemm8p(const u16* __restrict__ A,
                                                 const u16* __restrict__ Bt,
                                                 float* __restrict__ C, int K, int N, int gx,
                                                 u16* __restrict__ Qo, u16* __restrict__ Ko,
                                                 u16* __restrict__ Vo) {
  __shared__ alignas(16) u16 lsA[NBUF][256 * 32];
  __shared__ alignas(16) u16 lsB[NBUF][128 * 32];
  const int tid = threadIdx.x;
  const int lane = tid & 63;
  const int wid = tid >> 6;
  const int g = lane >> 4, lr = lane & 15;
  const int wm = wid >> 1, wn = wid & 1;

  const int nwg = gx << 4;
  const int bid = blockIdx.x;
  const int swz = (bid & 7) * (nwg >> 3) + (bid >> 3);
  const int m_idx = swz & 15, n_idx = swz >> 4;
  const size_t m0 = (size_t)m_idx * 256, n0 = (size_t)n_idx * 128;

  const int la0 = tid, la1 = 512 + tid;
  const int rowA0 = la0 >> 2, slA0 = la0 & 3;
  const int rowA1 = la1 >> 2, slA1 = la1 & 3;
  const int rowB = tid >> 2, slB = tid & 3;
  const u16* srcA0 = A + (m0 + rowA0) * K + ((slA0 ^ ((rowA0 >> 1) & 3)) << 3);
  const u16* srcA1 = A + (m0 + rowA1) * K + ((slA1 ^ ((rowA1 >> 1) & 3)) << 3);
  const u16* srcB = Bt + (n0 + rowB) * K + ((slB ^ ((rowB >> 1) & 3)) << 3);

#define STAGE(t, bufi)                                          \
  {                                                             \
    const int koff = (t) << 5;                                  \
    async16(srcA0 + koff, (char*)lsA[bufi] + la0 * 16);         \
    async16(srcA1 + koff, (char*)lsA[bufi] + la1 * 16);         \
    async16(srcB + koff, (char*)lsB[bufi] + tid * 16);          \
  }

  int ofsA[4], ofsB[4];
#pragma unroll
  for (int i = 0; i < 4; ++i) {
    int ra = wm * 64 + i * 16 + lr;
    ofsA[i] = ra * 64 + ((g ^ ((ra >> 1) & 3)) << 4);
    int rb = wn * 64 + i * 16 + lr;
    ofsB[i] = rb * 64 + ((g ^ ((rb >> 1) & 3)) << 4);
  }

  f32x4 acc[4][4] = {};
  const int nk = K >> 5;

#pragma unroll
  for (int t = 0; t < NBUF - 1; ++t) STAGE(t, t);
  asm volatile("s_waitcnt vmcnt(12)" ::: "memory");
  __builtin_amdgcn_s_barrier();

  int buf = 0;
#pragma unroll 1
  for (int kt = 0; kt < nk; ++kt) {
    bf16x8 af[4], bfr[4];
#pragma unroll
    for (int i = 0; i < 4; ++i) af[i] = *(const bf16x8*)((const char*)lsA[buf] + ofsA[i]);
#pragma unroll
    for (int j = 0; j < 4; ++j) bfr[j] = *(const bf16x8*)((const char*)lsB[buf] + ofsB[j]);
    const int st = kt + NBUF - 1;
    const int sbuf = buf == 0 ? NBUF - 1 : buf - 1;
    if (st < nk) STAGE(st, sbuf);
    __builtin_amdgcn_s_barrier();
    __builtin_amdgcn_s_setprio(1);
#pragma unroll
    for (int i = 0; i < 4; ++i)
#pragma unroll
      for (int j = 0; j < 4; ++j)
        acc[i][j] = __builtin_amdgcn_mfma_f32_16x16x32_bf16(af[i], bfr[j], acc[i][j], 0, 0, 0);
    __builtin_amdgcn_s_setprio(0);
    asm volatile("s_waitcnt vmcnt(12)" ::: "memory");
    __builtin_amdgcn_s_barrier();
    buf = buf == NBUF - 1 ? 0 : buf + 1;
  }
#undef STAGE

  if (EPI == 0) {
#pragma unroll
    for (int i = 0; i < 4; ++i)
#pragma unroll
      for (int j = 0; j < 4; ++j)
#pragma unroll
        for (int r = 0; r < 4; ++r) {
          size_t m = m0 + wm * 64 + i * 16 + 4 * g + r;
          size_t n = n0 + wn * 64 + j * 16 + lr;
          C[m * N + n] = acc[i][j][r];
        }
  } else {
    const int part = n_idx % 3, h = n_idx / 3;
    u16* dst = (part == 0) ? Qo : (part == 1 ? Ko : Vo);
#pragma unroll
    for (int i = 0; i < 4; ++i)
#pragma unroll
      for (int j = 0; j < 4; ++j)
#pragma unroll
        for (int r = 0; r < 4; ++r) {
          int m = (int)m0 + wm * 64 + i * 16 + 4 * g + r;
          int hd = wn * 64 + j * 16 + lr;
          int b = m >> 11, s = m & (S_ - 1);
          dst[((size_t)(b * H_ + h) * S_ + s) * HD_ + hd] = f2bf(acc[i][j][r]);
        }
  }
}

// ---------------- flash attention (unchanged) ----------------
__global__ __launch_bounds__(256) void attn_fwd(const u16* __restrict__ Q, const u16* __restrict__ K,
                                                const u16* __restrict__ VT, u16* __restrict__ X) {
  const int bx = blockIdx.x;
  const int bh = blockIdx.y;
  const int tid = threadIdx.x;
  const int lane = tid & 63, wid = tid >> 6;
  const int g = lane >> 4, lr = lane & 15;

  __shared__ alignas(16) u16 lsK[2][64 * 128];
  __shared__ alignas(16) u16 lsV[2][128 * 64];
  __shared__ alignas(16) u16 lsP[4][16 * 72];

  const u16* Qp = Q + (size_t)bh * S_ * HD_;
  const u16* Kp = K + (size_t)bh * S_ * HD_;
  const u16* Vp = VT + (size_t)bh * HD_ * S_;
  u16* myP = lsP[wid];
  const int b = bh >> 4, h = bh & 15;

  const float c1 = -0.057707802f;   // -0.04 * log2(e)
  const float c2 = -144.26950409f;  // -100 * log2(e)

#pragma unroll 1
  for (int pass = 0; pass < 2; ++pass) {
    const int qt = pass ? bx : (NT_ - 1 - bx);
    const int qrow = qt * 64 + wid * 16 + lr;
    const int qbase = qt * 64 + wid * 16 + 4 * g;

    bf16x8 qf[4];
#pragma unroll
    for (int kc = 0; kc < 4; ++kc)
      qf[kc] = *(const bf16x8*)(Qp + (size_t)qrow * HD_ + kc * 32 + g * 8);

    f32x4 o[8] = {};
    float psum[4] = {0.f, 0.f, 0.f, 0.f};

#pragma unroll
    for (int p = 0; p < 4; ++p) {
      int c = p * 256 + tid;
      int rowk = c >> 4;
      int wsk = ((c & 15) << 4) ^ ((rowk & 7) << 4);
      async16((const char*)Kp + (((size_t)rowk) << 8) + wsk, (char*)lsK[0] + c * 16);
      int rowv = c >> 3;
      int wsv = ((c & 7) << 4) ^ ((rowv & 7) << 4);
      async16((const char*)Vp + (size_t)rowv * (S_ * 2) + wsv, (char*)lsV[0] + c * 16);
    }
    __syncthreads();

    int cur = 0;
    for (int kt = 0; kt <= qt; ++kt) {
      if (kt < qt) {
        const int nxt = kt + 1;
#pragma unroll
        for (int p = 0; p < 4; ++p) {
          int c = p * 256 + tid;
          int rowk = c >> 4;
          int wsk = ((c & 15) << 4) ^ ((rowk & 7) << 4);
          async16((const char*)Kp + (((size_t)(nxt * 64 + rowk)) << 8) + wsk,
                  (char*)lsK[cur ^ 1] + c * 16);
          int rowv = c >> 3;
          int wsv = ((c & 7) << 4) ^ ((rowv & 7) << 4);
          async16((const char*)Vp + (size_t)rowv * (S_ * 2) + nxt * 128 + wsv,
                  (char*)lsV[cur ^ 1] + c * 16);
        }
      }
      f32x4 sc[4];
#pragma unroll
      for (int jn = 0; jn < 4; ++jn) {
        f32x4 a = {0.f, 0.f, 0.f, 0.f};
        const int row = jn * 16 + lr;
        const int sw = (row & 7) << 4;
#pragma unroll
        for (int kc = 0; kc < 4; ++kc) {
          int w = (kc * 64 + g * 16) ^ sw;
          bf16x8 kf = *(const bf16x8*)((const char*)lsK[cur] + row * 256 + w);
          a = __builtin_amdgcn_mfma_f32_16x16x32_bf16(qf[kc], kf, a, 0, 0, 0);
        }
        sc[jn] = a;
      }
#pragma unroll
      for (int jn = 0; jn < 4; ++jn) {
        int key = kt * 64 + jn * 16 + lr;
#pragma unroll
        for (int r = 0; r < 4; ++r) {
          float z = vexp2(c1 * sc[jn][r]);
          float p = vexp2(c2 * z * vrcp(1.f + z));
          if (key > qbase + r) p = 0.f;
          psum[r] += p;
          myP[(4 * g + r) * 72 + jn * 16 + lr] = f2bf(p);
        }
      }
#pragma unroll
      for (int kc = 0; kc < 2; ++kc) {
        bf16x8 pa = *(const bf16x8*)(myP + lr * 72 + kc * 32 + g * 8);
#pragma unroll
        for (int jh = 0; jh < 8; ++jh) {
          int row = jh * 16 + lr;
          int w = (kc * 64 + g * 16) ^ ((row & 7) << 4);
          bf16x8 vf = *(const bf16x8*)((const char*)lsV[cur] + row * 128 + w);
          o[jh] = __builtin_amdgcn_mfma_f32_16x16x32_bf16(pa, vf, o[jh], 0, 0, 0);
        }
      }
      __syncthreads();
      cur ^= 1;
    }
    float lsum[4];
#pragma unroll
    for (int r = 0; r < 4; ++r) {
      float s = psum[r];
#pragma unroll
      for (int msk = 1; msk < 16; msk <<= 1) s += __shfl_xor(s, msk, 64);
      lsum[r] = s;
    }
#pragma unroll
    for (int r = 0; r < 4; ++r) {
      float inv = 1.f / lsum[r];
      int s = qbase + r;
      u16* xp = X + ((size_t)(b * S_ + s)) * D_ + h * HD_;
#pragma unroll
      for (int jh = 0; jh < 8; ++jh) xp[jh * 16 + lr] = f2bf(o[jh][r] * inv);
    }
  }
}

extern "C" void kernel_launch(void* const* d_in, const int* in_sizes, int n_in,
                              void* d_out, int out_size, void* d_ws, size_t ws_size,
                              hipStream_t stream) {
  const float* inputs = (const float*)d_in[0];
  const float* w_in = (const float*)d_in[1];
  const float* w_out = (const float*)d_in[2];
  const float* rsin = (const float*)d_in[3];
  const float* rcos = (const float*)d_in[4];
  float* out = (float*)d_out;

  char* ws = (char*)d_ws;
  u16* bfA = (u16*)(ws);                   // (B*S, D) bf16
  u16* w_inT = (u16*)(ws + 16777216);      // (6144, 2048) bf16
  u16* Qraw = (u16*)(ws + 41943040);       // (B,H,S,HD)
  u16* Kraw = (u16*)(ws + 58720256);
  u16* Vraw = (u16*)(ws + 75497472);
  u16* VT = (u16*)(ws + 92274688);         // (B,H,HD,S)
  u16* Xbuf = (u16*)(ws);                  // reuse bfA region
  u16* w_outT = (u16*)(ws + 16777216);     // reuse w_inT region

  conv_f32_bf16<<<2048, 256, 0, stream>>>(inputs, bfA, B_ * S_ * D_);
  transpose_conv<<<dim3(6144 / 32, 2048 / 32), 256, 0, stream>>>(w_in, w_inT, 2048, 6144);
  gemm256<1><<<384, 512, 0, stream>>>(bfA, w_inT, nullptr, 2048, 6144, 24, Qraw, Kraw, Vraw);
  transpose_conv<<<dim3(2048 / 32, 2048 / 32), 256, 0, stream>>>(w_out, w_outT, 2048, 2048);
  rope_kernel<<<dim3(2048, 2), 256, 0, stream>>>(Qraw, Kraw, rsin, rcos);
  transpose_v<<<dim3(4, 64, 32), 256, 0, stream>>>(Vraw, VT);
  attn_fwd<<<dim3(NT_ / 2, 32), 256, 0, stream>>>(Qraw, Kraw, VT, Xbuf);
  gemm8p<0><<<256, 512, 0, stream>>>(Xbuf, w_outT, out, 2048, 2048, 16,
                                     nullptr, nullptr, nullptr);
}

// Round 5
// 294.793 us; speedup vs baseline: 1.5619x; 1.0157x over previous
//
#include <hip/hip_runtime.h>

#define B_ 2
#define S_ 2048
#define D_ 2048
#define H_ 16
#define HD_ 128
#define NT_ (S_ / 64)
#define NBUF 6

typedef unsigned short u16;
typedef __bf16 bf16x8 __attribute__((ext_vector_type(8)));
typedef float f32x4 __attribute__((ext_vector_type(4)));

__device__ __forceinline__ float bf2f(u16 u) {
  unsigned int x = ((unsigned int)u) << 16;
  return __builtin_bit_cast(float, x);
}
__device__ __forceinline__ u16 f2bf(float f) {
  unsigned int u = __builtin_bit_cast(unsigned int, f);
  u += 0x7fffu + ((u >> 16) & 1u);
  return (u16)(u >> 16);
}
__device__ __forceinline__ void async16(const void* g, void* l) {
  __builtin_amdgcn_global_load_lds((const __attribute__((address_space(1))) void*)g,
                                   (__attribute__((address_space(3))) void*)l, 16, 0, 0);
}
__device__ __forceinline__ float vexp2(float x) {
  float r;
  asm("v_exp_f32 %0, %1" : "=v"(r) : "v"(x));
  return r;
}
__device__ __forceinline__ float vrcp(float x) {
  float r;
  asm("v_rcp_f32 %0, %1" : "=v"(r) : "v"(x));
  return r;
}

// ---------------- elementwise fp32 -> bf16 ----------------
__global__ __launch_bounds__(256) void conv_f32_bf16(const float* __restrict__ in,
                                                     u16* __restrict__ outp, int n) {
  int idx = (blockIdx.x * 256 + threadIdx.x) * 4;
  int stride = gridDim.x * 256 * 4;
  for (; idx < n; idx += stride) {
    float4 v = *(const float4*)(in + idx);
    ushort4 ov = make_ushort4(f2bf(v.x), f2bf(v.y), f2bf(v.z), f2bf(v.w));
    *(ushort4*)(outp + idx) = ov;
  }
}

// ---------------- transpose + convert: in (R,C) fp32 -> out (C,R) bf16 ----------------
__global__ __launch_bounds__(256) void transpose_conv(const float* __restrict__ in,
                                                      u16* __restrict__ outp, int R, int C) {
  __shared__ float tile[32][33];
  int c0 = blockIdx.x * 32, r0 = blockIdx.y * 32;
  int tx = threadIdx.x & 31, ty = threadIdx.x >> 5;
#pragma unroll
  for (int yy = 0; yy < 32; yy += 8)
    tile[ty + yy][tx] = in[(size_t)(r0 + ty + yy) * C + c0 + tx];
  __syncthreads();
#pragma unroll
  for (int yy = 0; yy < 32; yy += 8)
    outp[(size_t)(c0 + ty + yy) * R + r0 + tx] = f2bf(tile[tx][ty + yy]);
}

// ---------------- bf16 per-head transpose: (S,HD) -> (HD,S) ----------------
__global__ __launch_bounds__(256) void transpose_v(const u16* __restrict__ in,
                                                   u16* __restrict__ outp) {
  __shared__ u16 tile[32][33];
  int bhh = blockIdx.z;
  const u16* ip = in + (size_t)bhh * S_ * HD_;
  u16* op = outp + (size_t)bhh * HD_ * S_;
  int hd0 = blockIdx.x * 32, s0 = blockIdx.y * 32;
  int tx = threadIdx.x & 31, ty = threadIdx.x >> 5;
#pragma unroll
  for (int yy = 0; yy < 32; yy += 8)
    tile[ty + yy][tx] = ip[(size_t)(s0 + ty + yy) * HD_ + hd0 + tx];
  __syncthreads();
#pragma unroll
  for (int yy = 0; yy < 32; yy += 8)
    op[(size_t)(hd0 + ty + yy) * S_ + s0 + tx] = tile[tx][ty + yy];
}

// ---------------- RoPE in place on (B,H,S,HD) bf16; blockIdx.y: 0 = Q (scaled), 1 = K ----------------
__global__ __launch_bounds__(256) void rope_kernel(u16* __restrict__ Q, u16* __restrict__ Kk,
                                                   const float* __restrict__ rsin,
                                                   const float* __restrict__ rcos) {
  int t = blockIdx.x * 256 + threadIdx.x;
  u16* base = blockIdx.y ? Kk : Q;
  float scale = blockIdx.y ? 1.0f : 0.08838834764831845f;  // 1/sqrt(128)
  int row = t >> 3, seg = t & 7;
  int s = row & (S_ - 1);
  int i0 = seg * 8;
  u16* p = base + (size_t)row * HD_;
  alignas(16) u16 x1[8], x2[8], o1[8], o2[8];
  *(uint4*)x1 = *(const uint4*)(p + i0);
  *(uint4*)x2 = *(const uint4*)(p + 64 + i0);
  alignas(16) float sn[8], cs[8];
  *(float4*)sn = *(const float4*)(rsin + s * 64 + i0);
  *(float4*)(sn + 4) = *(const float4*)(rsin + s * 64 + i0 + 4);
  *(float4*)cs = *(const float4*)(rcos + s * 64 + i0);
  *(float4*)(cs + 4) = *(const float4*)(rcos + s * 64 + i0 + 4);
#pragma unroll
  for (int j = 0; j < 8; ++j) {
    float a = bf2f(x1[j]), bb = bf2f(x2[j]);
    o1[j] = f2bf((a * cs[j] - bb * sn[j]) * scale);
    o2[j] = f2bf((bb * cs[j] + a * sn[j]) * scale);
  }
  *(uint4*)(p + i0) = *(uint4*)o1;
  *(uint4*)(p + 64 + i0) = *(uint4*)o2;
}

// ================= faithful m201-schedule 256x256 GEMM, BK=64, 8 phases =================
// C(M=4096,N) = A(M,K) * Bt(N,K)^T. 8 waves (2M x 4N), per-wave 128x64.
// 2 K-tiles (K=64 each) per iteration; 8 phases; each phase: ds_read quadrant frags,
// stage exactly 1 half-tile (16 KB, 2 global_load_lds/thread), barrier, lgkmcnt(0),
// setprio, 16 MFMA (one C-quadrant x K=64), vmcnt(4) at phases 4/8 only, barrier.
// LDS: 2 bufs x (A 256x64 + B 256x64) bf16 = 128 KiB. K-slot XOR swizzle (both sides).
#define BAR __builtin_amdgcn_s_barrier()
#define LGKM0                                          \
  {                                                    \
    asm volatile("s_waitcnt lgkmcnt(0)" ::: "memory"); \
    __builtin_amdgcn_sched_barrier(0);                 \
  }
#define VM4 asm volatile("s_waitcnt vmcnt(4)" ::: "memory")
#define VM0 asm volatile("s_waitcnt vmcnt(0)" ::: "memory")
#define P1 __builtin_amdgcn_s_setprio(1)
#define P0 __builtin_amdgcn_s_setprio(0)

template <int EPI>
__global__ __launch_bounds__(512, 1) void gemm256_8p(const u16* __restrict__ A,
                                                     const u16* __restrict__ Bt,
                                                     float* __restrict__ C, int K, int N,
                                                     int ntn, u16* __restrict__ Qo,
                                                     u16* __restrict__ Ko, u16* __restrict__ Vo) {
  __shared__ alignas(16) u16 lsA[2][256 * 64];
  __shared__ alignas(16) u16 lsB[2][256 * 64];
  const int tid = threadIdx.x;
  const int lane = tid & 63, wid = tid >> 6;
  const int g = lane >> 4, lr = lane & 15;
  const int wm = wid >> 2, wn = wid & 3;  // 2M x 4N

  // bijective XCD swizzle (nwg % 8 == 0), m-minor within XCD chunk (B-panel L2 locality)
  const int nwg = 16 * ntn;
  const int bid = blockIdx.x;
  const int swz = (bid & 7) * (nwg >> 3) + (bid >> 3);
  const int m_idx = swz & 15, n_idx = swz >> 4;
  const size_t m0 = (size_t)m_idx * 256, n0 = (size_t)n_idx * 256;

  // ---- staging sources: chunk idx = r*512+tid -> lds row idx>>3 (0..127), slot idx&7.
  // global k pre-swizzled: src slot = slot ^ (row & 7)  (involution; read applies same XOR)
  const int row0 = tid >> 3, sl0 = tid & 7;
  const int row1 = (512 + tid) >> 3, sl1 = tid & 7;  // (512+tid)&7 == tid&7
  const u16* pA0 = A + (m0 + row0) * K + ((sl0 ^ (row0 & 7)) << 3);
  const u16* pA1 = A + (m0 + row1) * K + ((sl1 ^ (row1 & 7)) << 3);
  const u16* pB0 = Bt + (n0 + row0) * K + ((sl0 ^ (row0 & 7)) << 3);
  const u16* pB1 = Bt + (n0 + row1) * K + ((sl1 ^ (row1 & 7)) << 3);
  const size_t hstep = (size_t)128 * K;  // advance 128 rows (half-tile)

#define STG_A(t, buf, half)                                                                   \
  {                                                                                           \
    async16(pA0 + (half) * hstep + (size_t)(t) * 64, (char*)lsA[buf] + (half) * 16384 + tid * 16); \
    async16(pA1 + (half) * hstep + (size_t)(t) * 64,                                          \
            (char*)lsA[buf] + (half) * 16384 + 8192 + tid * 16);                              \
  }
#define STG_B(t, buf, half)                                                                   \
  {                                                                                           \
    async16(pB0 + (half) * hstep + (size_t)(t) * 64, (char*)lsB[buf] + (half) * 16384 + tid * 16); \
    async16(pB1 + (half) * hstep + (size_t)(t) * 64,                                          \
            (char*)lsB[buf] + (half) * 16384 + 8192 + tid * 16);                              \
  }

  // ---- ds_read swizzle constants (row & 7 == lr & 7 for all frag rows)
  const int sw0 = ((g) ^ (lr & 7)) << 4;      // kk = 0
  const int sw1 = ((4 + g) ^ (lr & 7)) << 4;  // kk = 1

#define LDA(tb, mh)                                                              \
  {                                                                              \
    _Pragma("unroll") for (int i2 = 0; i2 < 4; ++i2) {                           \
      const char* _p = (const char*)lsA[tb] + (wm * 128 + (mh)*64 + i2 * 16 + lr) * 128; \
      aF[i2][0] = *(const bf16x8*)(_p + sw0);                                    \
      aF[i2][1] = *(const bf16x8*)(_p + sw1);                                    \
    }                                                                            \
  }
#define LDB(tb, dst, nh)                                                         \
  {                                                                              \
    _Pragma("unroll") for (int j2 = 0; j2 < 2; ++j2) {                           \
      const char* _p = (const char*)lsB[tb] + (wn * 64 + (nh)*32 + j2 * 16 + lr) * 128; \
      dst[j2][0] = *(const bf16x8*)(_p + sw0);                                   \
      dst[j2][1] = *(const bf16x8*)(_p + sw1);                                   \
    }                                                                            \
  }
#define MM(mh, nh, BB)                                                                        \
  {                                                                                           \
    _Pragma("unroll") for (int i2 = 0; i2 < 4; ++i2) _Pragma("unroll") for (int j2 = 0;      \
                                                                            j2 < 2; ++j2) {  \
      acc[(mh)*4 + i2][(nh)*2 + j2] = __builtin_amdgcn_mfma_f32_16x16x32_bf16(                \
          aF[i2][0], BB[j2][0], acc[(mh)*4 + i2][(nh)*2 + j2], 0, 0, 0);                      \
      acc[(mh)*4 + i2][(nh)*2 + j2] = __builtin_amdgcn_mfma_f32_16x16x32_bf16(                \
          aF[i2][1], BB[j2][1], acc[(mh)*4 + i2][(nh)*2 + j2], 0, 0, 0);                      \
    }                                                                                         \
  }

  f32x4 acc[8][4] = {};
  const int nk2 = K >> 7;  // iterations of 2 K-tiles; K=2048 -> 16

  // prologue: stage tile0 {A0,B1,B0,A1} + tile1 {A0,B1}; tile0 landed after vmcnt(4)
  STG_A(0, 0, 0);
  STG_B(0, 0, 1);
  STG_B(0, 0, 0);
  STG_A(0, 0, 1);
  STG_A(1, 1, 0);
  STG_B(1, 1, 1);
  VM4;
  BAR;

  bf16x8 aF[4][2], b0[2][2], b1[2][2];
#pragma unroll 1
  for (int it = 0; it < nk2 - 1; ++it) {
    const int t1 = 2 * it + 1, s2 = 2 * it + 2, s3 = 2 * it + 3;
    // ph1: buf0 (m0,n0); stage B0(t1)->buf1
    LDA(0, 0);
    LDB(0, b0, 0);
    STG_B(t1, 1, 0);
    BAR; LGKM0; P1; MM(0, 0, b0); P0; BAR;
    // ph2: (m0,n1); stage A1(t1)->buf1
    LDB(0, b1, 1);
    STG_A(t1, 1, 1);
    BAR; LGKM0; P1; MM(0, 1, b1); P0; BAR;
    // ph3: (m1,n1); stage A0(s2)->buf0
    LDA(0, 1);
    STG_A(s2, 0, 0);
    BAR; LGKM0; P1; MM(1, 1, b1); P0; BAR;
    // ph4: (m1,n0); stage B1(s2)->buf0; counted drain -> tile t1 fully resident
    STG_B(s2, 0, 1);
    BAR; LGKM0; P1; MM(1, 0, b0); P0;
    VM4;
    BAR;
    // ph5: buf1 (m0,n0); stage B0(s2)->buf0
    LDA(1, 0);
    LDB(1, b0, 0);
    STG_B(s2, 0, 0);
    BAR; LGKM0; P1; MM(0, 0, b0); P0; BAR;
    // ph6: (m0,n1); stage A1(s2)->buf0
    LDB(1, b1, 1);
    STG_A(s2, 0, 1);
    BAR; LGKM0; P1; MM(0, 1, b1); P0; BAR;
    // ph7: (m1,n1); stage A0(s3)->buf1
    LDA(1, 1);
    STG_A(s3, 1, 0);
    BAR; LGKM0; P1; MM(1, 1, b1); P0; BAR;
    // ph8: (m1,n0); stage B1(s3)->buf1; counted drain -> tile s2 fully resident
    STG_B(s3, 1, 1);
    BAR; LGKM0; P1; MM(1, 0, b0); P0;
    VM4;
    BAR;
  }
  {  // peeled last iteration: only tile (2it+1) halves B0,A1 still to stage
    const int t1 = 2 * (nk2 - 1) + 1;
    LDA(0, 0);
    LDB(0, b0, 0);
    STG_B(t1, 1, 0);
    BAR; LGKM0; P1; MM(0, 0, b0); P0; BAR;
    LDB(0, b1, 1);
    STG_A(t1, 1, 1);
    BAR; LGKM0; P1; MM(0, 1, b1); P0; BAR;
    LDA(0, 1);
    BAR; LGKM0; P1; MM(1, 1, b1); P0; BAR;
    BAR; LGKM0; P1; MM(1, 0, b0); P0;
    VM0;  // drain: tile t1's B0/A1 must be resident for ph5-8
    BAR;
    LDA(1, 0);
    LDB(1, b0, 0);
    BAR; LGKM0; P1; MM(0, 0, b0); P0; BAR;
    LDB(1, b1, 1);
    BAR; LGKM0; P1; MM(0, 1, b1); P0; BAR;
    LDA(1, 1);
    BAR; LGKM0; P1; MM(1, 1, b1); P0; BAR;
    BAR; LGKM0; P1; MM(1, 0, b0); P0; BAR;
  }
#undef STG_A
#undef STG_B
#undef LDA
#undef LDB
#undef MM

  if (EPI == 0) {
#pragma unroll
    for (int ai = 0; ai < 8; ++ai)
#pragma unroll
      for (int bj = 0; bj < 4; ++bj)
#pragma unroll
        for (int r = 0; r < 4; ++r) {
          size_t m = m0 + wm * 128 + (ai >> 2) * 64 + (ai & 3) * 16 + 4 * g + r;
          size_t n = n0 + wn * 64 + (bj >> 1) * 32 + (bj & 1) * 16 + lr;
          C[m * N + n] = acc[ai][bj][r];
        }
  } else {
    const int c = (int)(n0 >> 7) + (wn >> 1);  // 128-col chunk index (wave-uniform)
    const int h = c / 3, part = c % 3;
    u16* dst = (part == 0) ? Qo : (part == 1 ? Ko : Vo);
#pragma unroll
    for (int ai = 0; ai < 8; ++ai)
#pragma unroll
      for (int bj = 0; bj < 4; ++bj)
#pragma unroll
        for (int r = 0; r < 4; ++r) {
          int m = (int)m0 + wm * 128 + (ai >> 2) * 64 + (ai & 3) * 16 + 4 * g + r;
          int hd = (wn & 1) * 64 + (bj >> 1) * 32 + (bj & 1) * 16 + lr;
          int b = m >> 11, s = m & (S_ - 1);
          dst[((size_t)(b * H_ + h) * S_ + s) * HD_ + hd] = f2bf(acc[ai][bj][r]);
        }
  }
}

// ---------------- R3 deep-pipelined 256x128 GEMM (gemm2, unchanged control) ----------------
template <int EPI>
__global__ __launch_bounds__(512, 1) void gemm8p(const u16* __restrict__ A,
                                                 const u16* __restrict__ Bt,
                                                 float* __restrict__ C, int K, int N, int gx,
                                                 u16* __restrict__ Qo, u16* __restrict__ Ko,
                                                 u16* __restrict__ Vo) {
  __shared__ alignas(16) u16 lsA[NBUF][256 * 32];
  __shared__ alignas(16) u16 lsB[NBUF][128 * 32];
  const int tid = threadIdx.x;
  const int lane = tid & 63;
  const int wid = tid >> 6;
  const int g = lane >> 4, lr = lane & 15;
  const int wm = wid >> 1, wn = wid & 1;

  const int nwg = gx << 4;
  const int bid = blockIdx.x;
  const int swz = (bid & 7) * (nwg >> 3) + (bid >> 3);
  const int m_idx = swz & 15, n_idx = swz >> 4;
  const size_t m0 = (size_t)m_idx * 256, n0 = (size_t)n_idx * 128;

  const int la0 = tid, la1 = 512 + tid;
  const int rowA0 = la0 >> 2, slA0 = la0 & 3;
  const int rowA1 = la1 >> 2, slA1 = la1 & 3;
  const int rowB = tid >> 2, slB = tid & 3;
  const u16* srcA0 = A + (m0 + rowA0) * K + ((slA0 ^ ((rowA0 >> 1) & 3)) << 3);
  const u16* srcA1 = A + (m0 + rowA1) * K + ((slA1 ^ ((rowA1 >> 1) & 3)) << 3);
  const u16* srcB = Bt + (n0 + rowB) * K + ((slB ^ ((rowB >> 1) & 3)) << 3);

#define STAGE(t, bufi)                                  \
  {                                                     \
    const int koff = (t) << 5;                          \
    async16(srcA0 + koff, (char*)lsA[bufi] + la0 * 16); \
    async16(srcA1 + koff, (char*)lsA[bufi] + la1 * 16); \
    async16(srcB + koff, (char*)lsB[bufi] + tid * 16);  \
  }

  int ofsA[4], ofsB[4];
#pragma unroll
  for (int i = 0; i < 4; ++i) {
    int ra = wm * 64 + i * 16 + lr;
    ofsA[i] = ra * 64 + ((g ^ ((ra >> 1) & 3)) << 4);
    int rb = wn * 64 + i * 16 + lr;
    ofsB[i] = rb * 64 + ((g ^ ((rb >> 1) & 3)) << 4);
  }

  f32x4 acc[4][4] = {};
  const int nk = K >> 5;

#pragma unroll
  for (int t = 0; t < NBUF - 1; ++t) STAGE(t, t);
  asm volatile("s_waitcnt vmcnt(12)" ::: "memory");
  __builtin_amdgcn_s_barrier();

  int buf = 0;
#pragma unroll 1
  for (int kt = 0; kt < nk; ++kt) {
    bf16x8 af[4], bfr[4];
#pragma unroll
    for (int i = 0; i < 4; ++i) af[i] = *(const bf16x8*)((const char*)lsA[buf] + ofsA[i]);
#pragma unroll
    for (int j = 0; j < 4; ++j) bfr[j] = *(const bf16x8*)((const char*)lsB[buf] + ofsB[j]);
    const int st = kt + NBUF - 1;
    const int sbuf = buf == 0 ? NBUF - 1 : buf - 1;
    if (st < nk) STAGE(st, sbuf);
    __builtin_amdgcn_s_barrier();
    __builtin_amdgcn_s_setprio(1);
#pragma unroll
    for (int i = 0; i < 4; ++i)
#pragma unroll
      for (int j = 0; j < 4; ++j)
        acc[i][j] = __builtin_amdgcn_mfma_f32_16x16x32_bf16(af[i], bfr[j], acc[i][j], 0, 0, 0);
    __builtin_amdgcn_s_setprio(0);
    asm volatile("s_waitcnt vmcnt(12)" ::: "memory");
    __builtin_amdgcn_s_barrier();
    buf = buf == NBUF - 1 ? 0 : buf + 1;
  }
#undef STAGE

  if (EPI == 0) {
#pragma unroll
    for (int i = 0; i < 4; ++i)
#pragma unroll
      for (int j = 0; j < 4; ++j)
#pragma unroll
        for (int r = 0; r < 4; ++r) {
          size_t m = m0 + wm * 64 + i * 16 + 4 * g + r;
          size_t n = n0 + wn * 64 + j * 16 + lr;
          C[m * N + n] = acc[i][j][r];
        }
  } else {
    const int part = n_idx % 3, h = n_idx / 3;
    u16* dst = (part == 0) ? Qo : (part == 1 ? Ko : Vo);
#pragma unroll
    for (int i = 0; i < 4; ++i)
#pragma unroll
      for (int j = 0; j < 4; ++j)
#pragma unroll
        for (int r = 0; r < 4; ++r) {
          int m = (int)m0 + wm * 64 + i * 16 + 4 * g + r;
          int hd = wn * 64 + j * 16 + lr;
          int b = m >> 11, s = m & (S_ - 1);
          dst[((size_t)(b * H_ + h) * S_ + s) * HD_ + hd] = f2bf(acc[i][j][r]);
        }
  }
}

// ---------------- flash attention (unchanged) ----------------
__global__ __launch_bounds__(256) void attn_fwd(const u16* __restrict__ Q, const u16* __restrict__ K,
                                                const u16* __restrict__ VT, u16* __restrict__ X) {
  const int bx = blockIdx.x;
  const int bh = blockIdx.y;
  const int tid = threadIdx.x;
  const int lane = tid & 63, wid = tid >> 6;
  const int g = lane >> 4, lr = lane & 15;

  __shared__ alignas(16) u16 lsK[2][64 * 128];
  __shared__ alignas(16) u16 lsV[2][128 * 64];
  __shared__ alignas(16) u16 lsP[4][16 * 72];

  const u16* Qp = Q + (size_t)bh * S_ * HD_;
  const u16* Kp = K + (size_t)bh * S_ * HD_;
  const u16* Vp = VT + (size_t)bh * HD_ * S_;
  u16* myP = lsP[wid];
  const int b = bh >> 4, h = bh & 15;

  const float c1 = -0.057707802f;   // -0.04 * log2(e)
  const float c2 = -144.26950409f;  // -100 * log2(e)

#pragma unroll 1
  for (int pass = 0; pass < 2; ++pass) {
    const int qt = pass ? bx : (NT_ - 1 - bx);
    const int qrow = qt * 64 + wid * 16 + lr;
    const int qbase = qt * 64 + wid * 16 + 4 * g;

    bf16x8 qf[4];
#pragma unroll
    for (int kc = 0; kc < 4; ++kc)
      qf[kc] = *(const bf16x8*)(Qp + (size_t)qrow * HD_ + kc * 32 + g * 8);

    f32x4 o[8] = {};
    float psum[4] = {0.f, 0.f, 0.f, 0.f};

#pragma unroll
    for (int p = 0; p < 4; ++p) {
      int c = p * 256 + tid;
      int rowk = c >> 4;
      int wsk = ((c & 15) << 4) ^ ((rowk & 7) << 4);
      async16((const char*)Kp + (((size_t)rowk) << 8) + wsk, (char*)lsK[0] + c * 16);
      int rowv = c >> 3;
      int wsv = ((c & 7) << 4) ^ ((rowv & 7) << 4);
      async16((const char*)Vp + (size_t)rowv * (S_ * 2) + wsv, (char*)lsV[0] + c * 16);
    }
    __syncthreads();

    int cur = 0;
    for (int kt = 0; kt <= qt; ++kt) {
      if (kt < qt) {
        const int nxt = kt + 1;
#pragma unroll
        for (int p = 0; p < 4; ++p) {
          int c = p * 256 + tid;
          int rowk = c >> 4;
          int wsk = ((c & 15) << 4) ^ ((rowk & 7) << 4);
          async16((const char*)Kp + (((size_t)(nxt * 64 + rowk)) << 8) + wsk,
                  (char*)lsK[cur ^ 1] + c * 16);
          int rowv = c >> 3;
          int wsv = ((c & 7) << 4) ^ ((rowv & 7) << 4);
          async16((const char*)Vp + (size_t)rowv * (S_ * 2) + nxt * 128 + wsv,
                  (char*)lsV[cur ^ 1] + c * 16);
        }
      }
      f32x4 sc[4];
#pragma unroll
      for (int jn = 0; jn < 4; ++jn) {
        f32x4 a = {0.f, 0.f, 0.f, 0.f};
        const int row = jn * 16 + lr;
        const int sw = (row & 7) << 4;
#pragma unroll
        for (int kc = 0; kc < 4; ++kc) {
          int w = (kc * 64 + g * 16) ^ sw;
          bf16x8 kf = *(const bf16x8*)((const char*)lsK[cur] + row * 256 + w);
          a = __builtin_amdgcn_mfma_f32_16x16x32_bf16(qf[kc], kf, a, 0, 0, 0);
        }
        sc[jn] = a;
      }
#pragma unroll
      for (int jn = 0; jn < 4; ++jn) {
        int key = kt * 64 + jn * 16 + lr;
#pragma unroll
        for (int r = 0; r < 4; ++r) {
          float z = vexp2(c1 * sc[jn][r]);
          float p = vexp2(c2 * z * vrcp(1.f + z));
          if (key > qbase + r) p = 0.f;
          psum[r] += p;
          myP[(4 * g + r) * 72 + jn * 16 + lr] = f2bf(p);
        }
      }
#pragma unroll
      for (int kc = 0; kc < 2; ++kc) {
        bf16x8 pa = *(const bf16x8*)(myP + lr * 72 + kc * 32 + g * 8);
#pragma unroll
        for (int jh = 0; jh < 8; ++jh) {
          int row = jh * 16 + lr;
          int w = (kc * 64 + g * 16) ^ ((row & 7) << 4);
          bf16x8 vf = *(const bf16x8*)((const char*)lsV[cur] + row * 128 + w);
          o[jh] = __builtin_amdgcn_mfma_f32_16x16x32_bf16(pa, vf, o[jh], 0, 0, 0);
        }
      }
      __syncthreads();
      cur ^= 1;
    }
    float lsum[4];
#pragma unroll
    for (int r = 0; r < 4; ++r) {
      float s = psum[r];
#pragma unroll
      for (int msk = 1; msk < 16; msk <<= 1) s += __shfl_xor(s, msk, 64);
      lsum[r] = s;
    }
#pragma unroll
    for (int r = 0; r < 4; ++r) {
      float inv = 1.f / lsum[r];
      int s = qbase + r;
      u16* xp = X + ((size_t)(b * S_ + s)) * D_ + h * HD_;
#pragma unroll
      for (int jh = 0; jh < 8; ++jh) xp[jh * 16 + lr] = f2bf(o[jh][r] * inv);
    }
  }
}

extern "C" void kernel_launch(void* const* d_in, const int* in_sizes, int n_in,
                              void* d_out, int out_size, void* d_ws, size_t ws_size,
                              hipStream_t stream) {
  const float* inputs = (const float*)d_in[0];
  const float* w_in = (const float*)d_in[1];
  const float* w_out = (const float*)d_in[2];
  const float* rsin = (const float*)d_in[3];
  const float* rcos = (const float*)d_in[4];
  float* out = (float*)d_out;

  char* ws = (char*)d_ws;
  u16* bfA = (u16*)(ws);                   // (B*S, D) bf16
  u16* w_inT = (u16*)(ws + 16777216);      // (6144, 2048) bf16
  u16* Qraw = (u16*)(ws + 41943040);       // (B,H,S,HD)
  u16* Kraw = (u16*)(ws + 58720256);
  u16* Vraw = (u16*)(ws + 75497472);
  u16* VT = (u16*)(ws + 92274688);         // (B,H,HD,S)
  u16* Xbuf = (u16*)(ws);                  // reuse bfA region
  u16* w_outT = (u16*)(ws + 16777216);     // reuse w_inT region

  conv_f32_bf16<<<2048, 256, 0, stream>>>(inputs, bfA, B_ * S_ * D_);
  transpose_conv<<<dim3(6144 / 32, 2048 / 32), 256, 0, stream>>>(w_in, w_inT, 2048, 6144);
  gemm256_8p<1><<<384, 512, 0, stream>>>(bfA, w_inT, nullptr, 2048, 6144, 24,
                                         Qraw, Kraw, Vraw);
  transpose_conv<<<dim3(2048 / 32, 2048 / 32), 256, 0, stream>>>(w_out, w_outT, 2048, 2048);
  rope_kernel<<<dim3(2048, 2), 256, 0, stream>>>(Qraw, Kraw, rsin, rcos);
  transpose_v<<<dim3(4, 64, 32), 256, 0, stream>>>(Vraw, VT);
  attn_fwd<<<dim3(NT_ / 2, 32), 256, 0, stream>>>(Qraw, Kraw, VT, Xbuf);
  gemm8p<0><<<256, 512, 0, stream>>>(Xbuf, w_outT, out, 2048, 2048, 16,
                                     nullptr, nullptr, nullptr);
}

// Round 6
// 288.306 us; speedup vs baseline: 1.5970x; 1.0225x over previous
//
#include <hip/hip_runtime.h>

#define B_ 2
#define S_ 2048
#define D_ 2048
#define H_ 16
#define HD_ 128
#define NT_ (S_ / 64)
#define NBUF 6

typedef unsigned short u16;
typedef __bf16 bf16x8 __attribute__((ext_vector_type(8)));
typedef float f32x4 __attribute__((ext_vector_type(4)));

__device__ __forceinline__ float bf2f(u16 u) {
  unsigned int x = ((unsigned int)u) << 16;
  return __builtin_bit_cast(float, x);
}
__device__ __forceinline__ u16 f2bf(float f) {
  unsigned int u = __builtin_bit_cast(unsigned int, f);
  u += 0x7fffu + ((u >> 16) & 1u);
  return (u16)(u >> 16);
}
__device__ __forceinline__ void async16(const void* g, void* l) {
  __builtin_amdgcn_global_load_lds((const __attribute__((address_space(1))) void*)g,
                                   (__attribute__((address_space(3))) void*)l, 16, 0, 0);
}
__device__ __forceinline__ float vexp2(float x) {
  float r;
  asm("v_exp_f32 %0, %1" : "=v"(r) : "v"(x));
  return r;
}
__device__ __forceinline__ float vrcp(float x) {
  float r;
  asm("v_rcp_f32 %0, %1" : "=v"(r) : "v"(x));
  return r;
}

// ---------------- elementwise fp32 -> bf16 ----------------
__global__ __launch_bounds__(256) void conv_f32_bf16(const float* __restrict__ in,
                                                     u16* __restrict__ outp, int n) {
  int idx = (blockIdx.x * 256 + threadIdx.x) * 4;
  int stride = gridDim.x * 256 * 4;
  for (; idx < n; idx += stride) {
    float4 v = *(const float4*)(in + idx);
    ushort4 ov = make_ushort4(f2bf(v.x), f2bf(v.y), f2bf(v.z), f2bf(v.w));
    *(ushort4*)(outp + idx) = ov;
  }
}

// ---------------- transpose + convert: in (R,C) fp32 -> out (C,R) bf16 (generic) ----------------
__global__ __launch_bounds__(256) void transpose_conv(const float* __restrict__ in,
                                                      u16* __restrict__ outp, int R, int C) {
  __shared__ float tile[32][33];
  int c0 = blockIdx.x * 32, r0 = blockIdx.y * 32;
  int tx = threadIdx.x & 31, ty = threadIdx.x >> 5;
#pragma unroll
  for (int yy = 0; yy < 32; yy += 8)
    tile[ty + yy][tx] = in[(size_t)(r0 + ty + yy) * C + c0 + tx];
  __syncthreads();
#pragma unroll
  for (int yy = 0; yy < 32; yy += 8)
    outp[(size_t)(c0 + ty + yy) * R + r0 + tx] = f2bf(tile[tx][ty + yy]);
}

// ---------------- w_in transpose+convert with sigma column permutation ----------------
// out row n = chunk c*128 + p holds w_in column f = (c/3)*384 + (c%3)*128 + d(p)
// d(p) = (p>>6)*32 + (((p>>4)&3)>>1)*16 + (((p>>4)&3)&1)*64 + (p&15)
// chosen so the GEMM epilogue's lane fragment pairs (bj, bj+1) are RoPE pairs (d, d+64).
__global__ __launch_bounds__(256) void transpose_win(const float* __restrict__ in,
                                                     u16* __restrict__ outp) {
  __shared__ float tile[32][33];
  int n0 = blockIdx.x * 32, k0 = blockIdx.y * 32;
  int tx = threadIdx.x & 31, ty = threadIdx.x >> 5;
  int n = n0 + tx;
  int cc = n >> 7, p = n & 127;
  int q = (p >> 4) & 3;
  int d = ((p >> 6) << 5) + ((q >> 1) << 4) + ((q & 1) << 6) + (p & 15);
  int f = (cc / 3) * 384 + (cc % 3) * 128 + d;
#pragma unroll
  for (int yy = 0; yy < 32; yy += 8)
    tile[ty + yy][tx] = in[(size_t)(k0 + ty + yy) * 6144 + f];
  __syncthreads();
#pragma unroll
  for (int yy = 0; yy < 32; yy += 8)
    outp[(size_t)(n0 + ty + yy) * 2048 + k0 + tx] = f2bf(tile[tx][ty + yy]);
}

// ================= m201-schedule 256x256 GEMM, BK=64, 8 phases =================
// EPI==1 epilogue: in-register RoPE on Q/K (sigma-permuted columns) + direct
// transposed V write (B,H,HD,S). EPI==0: plain fp32 C.
#define BAR __builtin_amdgcn_s_barrier()
#define LGKM0                                          \
  {                                                    \
    asm volatile("s_waitcnt lgkmcnt(0)" ::: "memory"); \
    __builtin_amdgcn_sched_barrier(0);                 \
  }
#define VM4 asm volatile("s_waitcnt vmcnt(4)" ::: "memory")
#define VM0 asm volatile("s_waitcnt vmcnt(0)" ::: "memory")
#define P1 __builtin_amdgcn_s_setprio(1)
#define P0 __builtin_amdgcn_s_setprio(0)

template <int EPI>
__global__ __launch_bounds__(512, 1) void gemm256_8p(
    const u16* __restrict__ A, const u16* __restrict__ Bt, float* __restrict__ C, int K, int N,
    int ntn, u16* __restrict__ Qo, u16* __restrict__ Ko, u16* __restrict__ Vo,
    const float* __restrict__ rsin, const float* __restrict__ rcos) {
  __shared__ alignas(16) u16 lsA[2][256 * 64];
  __shared__ alignas(16) u16 lsB[2][256 * 64];
  const int tid = threadIdx.x;
  const int lane = tid & 63, wid = tid >> 6;
  const int g = lane >> 4, lr = lane & 15;
  const int wm = wid >> 2, wn = wid & 3;  // 2M x 4N

  const int nwg = 16 * ntn;
  const int bid = blockIdx.x;
  const int swz = (bid & 7) * (nwg >> 3) + (bid >> 3);
  const int m_idx = swz & 15, n_idx = swz >> 4;
  const size_t m0 = (size_t)m_idx * 256, n0 = (size_t)n_idx * 256;

  const int row0 = tid >> 3, sl0 = tid & 7;
  const int row1 = (512 + tid) >> 3, sl1 = tid & 7;
  const u16* pA0 = A + (m0 + row0) * K + ((sl0 ^ (row0 & 7)) << 3);
  const u16* pA1 = A + (m0 + row1) * K + ((sl1 ^ (row1 & 7)) << 3);
  const u16* pB0 = Bt + (n0 + row0) * K + ((sl0 ^ (row0 & 7)) << 3);
  const u16* pB1 = Bt + (n0 + row1) * K + ((sl1 ^ (row1 & 7)) << 3);
  const size_t hstep = (size_t)128 * K;

#define STG_A(t, buf, half)                                                                        \
  {                                                                                                \
    async16(pA0 + (half)*hstep + (size_t)(t)*64, (char*)lsA[buf] + (half)*16384 + tid * 16);       \
    async16(pA1 + (half)*hstep + (size_t)(t)*64, (char*)lsA[buf] + (half)*16384 + 8192 + tid * 16); \
  }
#define STG_B(t, buf, half)                                                                        \
  {                                                                                                \
    async16(pB0 + (half)*hstep + (size_t)(t)*64, (char*)lsB[buf] + (half)*16384 + tid * 16);       \
    async16(pB1 + (half)*hstep + (size_t)(t)*64, (char*)lsB[buf] + (half)*16384 + 8192 + tid * 16); \
  }

  const int sw0 = ((g) ^ (lr & 7)) << 4;
  const int sw1 = ((4 + g) ^ (lr & 7)) << 4;

#define LDA(tb, mh)                                                                      \
  {                                                                                      \
    _Pragma("unroll") for (int i2 = 0; i2 < 4; ++i2) {                                   \
      const char* _p = (const char*)lsA[tb] + (wm * 128 + (mh)*64 + i2 * 16 + lr) * 128; \
      aF[i2][0] = *(const bf16x8*)(_p + sw0);                                            \
      aF[i2][1] = *(const bf16x8*)(_p + sw1);                                            \
    }                                                                                    \
  }
#define LDB(tb, dst, nh)                                                                \
  {                                                                                     \
    _Pragma("unroll") for (int j2 = 0; j2 < 2; ++j2) {                                  \
      const char* _p = (const char*)lsB[tb] + (wn * 64 + (nh)*32 + j2 * 16 + lr) * 128; \
      dst[j2][0] = *(const bf16x8*)(_p + sw0);                                          \
      dst[j2][1] = *(const bf16x8*)(_p + sw1);                                          \
    }                                                                                   \
  }
#define MM(mh, nh, BB)                                                                       \
  {                                                                                          \
    _Pragma("unroll") for (int i2 = 0; i2 < 4; ++i2) _Pragma("unroll") for (int j2 = 0;     \
                                                                            j2 < 2; ++j2) { \
      acc[(mh)*4 + i2][(nh)*2 + j2] = __builtin_amdgcn_mfma_f32_16x16x32_bf16(               \
          aF[i2][0], BB[j2][0], acc[(mh)*4 + i2][(nh)*2 + j2], 0, 0, 0);                     \
      acc[(mh)*4 + i2][(nh)*2 + j2] = __builtin_amdgcn_mfma_f32_16x16x32_bf16(               \
          aF[i2][1], BB[j2][1], acc[(mh)*4 + i2][(nh)*2 + j2], 0, 0, 0);                     \
    }                                                                                        \
  }

  f32x4 acc[8][4] = {};
  const int nk2 = K >> 7;

  STG_A(0, 0, 0);
  STG_B(0, 0, 1);
  STG_B(0, 0, 0);
  STG_A(0, 0, 1);
  STG_A(1, 1, 0);
  STG_B(1, 1, 1);
  VM4;
  BAR;

  bf16x8 aF[4][2], b0[2][2], b1[2][2];
#pragma unroll 1
  for (int it = 0; it < nk2 - 1; ++it) {
    const int t1 = 2 * it + 1, s2 = 2 * it + 2, s3 = 2 * it + 3;
    LDA(0, 0);
    LDB(0, b0, 0);
    STG_B(t1, 1, 0);
    BAR; LGKM0; P1; MM(0, 0, b0); P0; BAR;
    LDB(0, b1, 1);
    STG_A(t1, 1, 1);
    BAR; LGKM0; P1; MM(0, 1, b1); P0; BAR;
    LDA(0, 1);
    STG_A(s2, 0, 0);
    BAR; LGKM0; P1; MM(1, 1, b1); P0; BAR;
    STG_B(s2, 0, 1);
    BAR; LGKM0; P1; MM(1, 0, b0); P0;
    VM4;
    BAR;
    LDA(1, 0);
    LDB(1, b0, 0);
    STG_B(s2, 0, 0);
    BAR; LGKM0; P1; MM(0, 0, b0); P0; BAR;
    LDB(1, b1, 1);
    STG_A(s2, 0, 1);
    BAR; LGKM0; P1; MM(0, 1, b1); P0; BAR;
    LDA(1, 1);
    STG_A(s3, 1, 0);
    BAR; LGKM0; P1; MM(1, 1, b1); P0; BAR;
    STG_B(s3, 1, 1);
    BAR; LGKM0; P1; MM(1, 0, b0); P0;
    VM4;
    BAR;
  }
  {
    const int t1 = 2 * (nk2 - 1) + 1;
    LDA(0, 0);
    LDB(0, b0, 0);
    STG_B(t1, 1, 0);
    BAR; LGKM0; P1; MM(0, 0, b0); P0; BAR;
    LDB(0, b1, 1);
    STG_A(t1, 1, 1);
    BAR; LGKM0; P1; MM(0, 1, b1); P0; BAR;
    LDA(0, 1);
    BAR; LGKM0; P1; MM(1, 1, b1); P0; BAR;
    BAR; LGKM0; P1; MM(1, 0, b0); P0;
    VM0;
    BAR;
    LDA(1, 0);
    LDB(1, b0, 0);
    BAR; LGKM0; P1; MM(0, 0, b0); P0; BAR;
    LDB(1, b1, 1);
    BAR; LGKM0; P1; MM(0, 1, b1); P0; BAR;
    LDA(1, 1);
    BAR; LGKM0; P1; MM(1, 1, b1); P0; BAR;
    BAR; LGKM0; P1; MM(1, 0, b0); P0; BAR;
  }
#undef STG_A
#undef STG_B
#undef LDA
#undef LDB
#undef MM

  if (EPI == 0) {
#pragma unroll
    for (int ai = 0; ai < 8; ++ai)
#pragma unroll
      for (int bj = 0; bj < 4; ++bj)
#pragma unroll
        for (int r = 0; r < 4; ++r) {
          size_t m = m0 + wm * 128 + (ai >> 2) * 64 + (ai & 3) * 16 + 4 * g + r;
          size_t n = n0 + wn * 64 + (bj >> 1) * 32 + (bj & 1) * 16 + lr;
          C[m * N + n] = acc[ai][bj][r];
        }
  } else {
    // chunk c (128 cols, wave-uniform) -> (h, part). Columns are sigma-permuted:
    // lane position (wn&1, bj, lr) holds original d = (wn&1)*32 + (bj>>1)*16 + (bj&1)*64 + lr
    const int c = (int)(n0 >> 7) + (wn >> 1);
    const int h = c / 3, part = c % 3;
    const int wn1 = wn & 1;
    if (part == 2) {
      // V: un-permute, write transposed (B,H,HD,S); r = 4 consecutive s -> ushort4
#pragma unroll
      for (int ai = 0; ai < 8; ++ai) {
        int m = (int)m0 + wm * 128 + (ai >> 2) * 64 + (ai & 3) * 16 + 4 * g;
        int b = m >> 11, s = m & (S_ - 1);
#pragma unroll
        for (int bj = 0; bj < 4; ++bj) {
          int hd = wn1 * 32 + ((bj >> 1) << 4) + ((bj & 1) << 6) + lr;
          ushort4 pk;
          pk.x = f2bf(acc[ai][bj][0]);
          pk.y = f2bf(acc[ai][bj][1]);
          pk.z = f2bf(acc[ai][bj][2]);
          pk.w = f2bf(acc[ai][bj][3]);
          *(ushort4*)(Vo + ((size_t)(b * H_ + h) * HD_ + hd) * S_ + s) = pk;
        }
      }
    } else {
      // Q/K: in-register RoPE; pairs (bj=2t, bj=2t+1) = (d, d+64), d = wn1*32 + t*16 + lr
      u16* dstp = (part == 0) ? Qo : Ko;
      const float scl = (part == 0) ? 0.08838834764831845f : 1.0f;  // 1/sqrt(HD) on Q
#pragma unroll
      for (int ai = 0; ai < 8; ++ai) {
        int mbase = (int)m0 + wm * 128 + (ai >> 2) * 64 + (ai & 3) * 16 + 4 * g;
#pragma unroll
        for (int r = 0; r < 4; ++r) {
          int m = mbase + r;
          int b = m >> 11, s = m & (S_ - 1);
          const float* srow = rsin + s * 64;
          const float* crow = rcos + s * 64;
          u16* op = dstp + ((size_t)(b * H_ + h) * S_ + s) * HD_;
#pragma unroll
          for (int t = 0; t < 2; ++t) {
            int d = wn1 * 32 + t * 16 + lr;
            float cv = crow[d] * scl, sv = srow[d] * scl;
            float x1 = acc[ai][t * 2][r], x2 = acc[ai][t * 2 + 1][r];
            op[d] = f2bf(x1 * cv - x2 * sv);
            op[d + 64] = f2bf(x2 * cv + x1 * sv);
          }
        }
      }
    }
  }
}

// ---------------- R3 deep-pipelined 256x128 GEMM (gemm2) ----------------
template <int EPI>
__global__ __launch_bounds__(512, 1) void gemm8p(const u16* __restrict__ A,
                                                 const u16* __restrict__ Bt,
                                                 float* __restrict__ C, int K, int N, int gx,
                                                 u16* __restrict__ Qo, u16* __restrict__ Ko,
                                                 u16* __restrict__ Vo) {
  __shared__ alignas(16) u16 lsA[NBUF][256 * 32];
  __shared__ alignas(16) u16 lsB[NBUF][128 * 32];
  const int tid = threadIdx.x;
  const int lane = tid & 63;
  const int wid = tid >> 6;
  const int g = lane >> 4, lr = lane & 15;
  const int wm = wid >> 1, wn = wid & 1;

  const int nwg = gx << 4;
  const int bid = blockIdx.x;
  const int swz = (bid & 7) * (nwg >> 3) + (bid >> 3);
  const int m_idx = swz & 15, n_idx = swz >> 4;
  const size_t m0 = (size_t)m_idx * 256, n0 = (size_t)n_idx * 128;

  const int la0 = tid, la1 = 512 + tid;
  const int rowA0 = la0 >> 2, slA0 = la0 & 3;
  const int rowA1 = la1 >> 2, slA1 = la1 & 3;
  const int rowB = tid >> 2, slB = tid & 3;
  const u16* srcA0 = A + (m0 + rowA0) * K + ((slA0 ^ ((rowA0 >> 1) & 3)) << 3);
  const u16* srcA1 = A + (m0 + rowA1) * K + ((slA1 ^ ((rowA1 >> 1) & 3)) << 3);
  const u16* srcB = Bt + (n0 + rowB) * K + ((slB ^ ((rowB >> 1) & 3)) << 3);

#define STAGE(t, bufi)                                  \
  {                                                     \
    const int koff = (t) << 5;                          \
    async16(srcA0 + koff, (char*)lsA[bufi] + la0 * 16); \
    async16(srcA1 + koff, (char*)lsA[bufi] + la1 * 16); \
    async16(srcB + koff, (char*)lsB[bufi] + tid * 16);  \
  }

  int ofsA[4], ofsB[4];
#pragma unroll
  for (int i = 0; i < 4; ++i) {
    int ra = wm * 64 + i * 16 + lr;
    ofsA[i] = ra * 64 + ((g ^ ((ra >> 1) & 3)) << 4);
    int rb = wn * 64 + i * 16 + lr;
    ofsB[i] = rb * 64 + ((g ^ ((rb >> 1) & 3)) << 4);
  }

  f32x4 acc[4][4] = {};
  const int nk = K >> 5;

#pragma unroll
  for (int t = 0; t < NBUF - 1; ++t) STAGE(t, t);
  asm volatile("s_waitcnt vmcnt(12)" ::: "memory");
  __builtin_amdgcn_s_barrier();

  int buf = 0;
#pragma unroll 1
  for (int kt = 0; kt < nk; ++kt) {
    bf16x8 af[4], bfr[4];
#pragma unroll
    for (int i = 0; i < 4; ++i) af[i] = *(const bf16x8*)((const char*)lsA[buf] + ofsA[i]);
#pragma unroll
    for (int j = 0; j < 4; ++j) bfr[j] = *(const bf16x8*)((const char*)lsB[buf] + ofsB[j]);
    const int st = kt + NBUF - 1;
    const int sbuf = buf == 0 ? NBUF - 1 : buf - 1;
    if (st < nk) STAGE(st, sbuf);
    __builtin_amdgcn_s_barrier();
    __builtin_amdgcn_s_setprio(1);
#pragma unroll
    for (int i = 0; i < 4; ++i)
#pragma unroll
      for (int j = 0; j < 4; ++j)
        acc[i][j] = __builtin_amdgcn_mfma_f32_16x16x32_bf16(af[i], bfr[j], acc[i][j], 0, 0, 0);
    __builtin_amdgcn_s_setprio(0);
    asm volatile("s_waitcnt vmcnt(12)" ::: "memory");
    __builtin_amdgcn_s_barrier();
    buf = buf == NBUF - 1 ? 0 : buf + 1;
  }
#undef STAGE

  if (EPI == 0) {
#pragma unroll
    for (int i = 0; i < 4; ++i)
#pragma unroll
      for (int j = 0; j < 4; ++j)
#pragma unroll
        for (int r = 0; r < 4; ++r) {
          size_t m = m0 + wm * 64 + i * 16 + 4 * g + r;
          size_t n = n0 + wn * 64 + j * 16 + lr;
          C[m * N + n] = acc[i][j][r];
        }
  } else {
    const int part = n_idx % 3, h = n_idx / 3;
    u16* dst = (part == 0) ? Qo : (part == 1 ? Ko : Vo);
#pragma unroll
    for (int i = 0; i < 4; ++i)
#pragma unroll
      for (int j = 0; j < 4; ++j)
#pragma unroll
        for (int r = 0; r < 4; ++r) {
          int m = (int)m0 + wm * 64 + i * 16 + 4 * g + r;
          int hd = wn * 64 + j * 16 + lr;
          int b = m >> 11, s = m & (S_ - 1);
          dst[((size_t)(b * H_ + h) * S_ + s) * HD_ + hd] = f2bf(acc[i][j][r]);
        }
  }
}

// ---------------- flash attention (unchanged) ----------------
__global__ __launch_bounds__(256) void attn_fwd(const u16* __restrict__ Q, const u16* __restrict__ K,
                                                const u16* __restrict__ VT, u16* __restrict__ X) {
  const int bx = blockIdx.x;
  const int bh = blockIdx.y;
  const int tid = threadIdx.x;
  const int lane = tid & 63, wid = tid >> 6;
  const int g = lane >> 4, lr = lane & 15;

  __shared__ alignas(16) u16 lsK[2][64 * 128];
  __shared__ alignas(16) u16 lsV[2][128 * 64];
  __shared__ alignas(16) u16 lsP[4][16 * 72];

  const u16* Qp = Q + (size_t)bh * S_ * HD_;
  const u16* Kp = K + (size_t)bh * S_ * HD_;
  const u16* Vp = VT + (size_t)bh * HD_ * S_;
  u16* myP = lsP[wid];
  const int b = bh >> 4, h = bh & 15;

  const float c1 = -0.057707802f;   // -0.04 * log2(e)
  const float c2 = -144.26950409f;  // -100 * log2(e)

#pragma unroll 1
  for (int pass = 0; pass < 2; ++pass) {
    const int qt = pass ? bx : (NT_ - 1 - bx);
    const int qrow = qt * 64 + wid * 16 + lr;
    const int qbase = qt * 64 + wid * 16 + 4 * g;

    bf16x8 qf[4];
#pragma unroll
    for (int kc = 0; kc < 4; ++kc)
      qf[kc] = *(const bf16x8*)(Qp + (size_t)qrow * HD_ + kc * 32 + g * 8);

    f32x4 o[8] = {};
    float psum[4] = {0.f, 0.f, 0.f, 0.f};

#pragma unroll
    for (int p = 0; p < 4; ++p) {
      int c = p * 256 + tid;
      int rowk = c >> 4;
      int wsk = ((c & 15) << 4) ^ ((rowk & 7) << 4);
      async16((const char*)Kp + (((size_t)rowk) << 8) + wsk, (char*)lsK[0] + c * 16);
      int rowv = c >> 3;
      int wsv = ((c & 7) << 4) ^ ((rowv & 7) << 4);
      async16((const char*)Vp + (size_t)rowv * (S_ * 2) + wsv, (char*)lsV[0] + c * 16);
    }
    __syncthreads();

    int cur = 0;
    for (int kt = 0; kt <= qt; ++kt) {
      if (kt < qt) {
        const int nxt = kt + 1;
#pragma unroll
        for (int p = 0; p < 4; ++p) {
          int c = p * 256 + tid;
          int rowk = c >> 4;
          int wsk = ((c & 15) << 4) ^ ((rowk & 7) << 4);
          async16((const char*)Kp + (((size_t)(nxt * 64 + rowk)) << 8) + wsk,
                  (char*)lsK[cur ^ 1] + c * 16);
          int rowv = c >> 3;
          int wsv = ((c & 7) << 4) ^ ((rowv & 7) << 4);
          async16((const char*)Vp + (size_t)rowv * (S_ * 2) + nxt * 128 + wsv,
                  (char*)lsV[cur ^ 1] + c * 16);
        }
      }
      f32x4 sc[4];
#pragma unroll
      for (int jn = 0; jn < 4; ++jn) {
        f32x4 a = {0.f, 0.f, 0.f, 0.f};
        const int row = jn * 16 + lr;
        const int sw = (row & 7) << 4;
#pragma unroll
        for (int kc = 0; kc < 4; ++kc) {
          int w = (kc * 64 + g * 16) ^ sw;
          bf16x8 kf = *(const bf16x8*)((const char*)lsK[cur] + row * 256 + w);
          a = __builtin_amdgcn_mfma_f32_16x16x32_bf16(qf[kc], kf, a, 0, 0, 0);
        }
        sc[jn] = a;
      }
#pragma unroll
      for (int jn = 0; jn < 4; ++jn) {
        int key = kt * 64 + jn * 16 + lr;
#pragma unroll
        for (int r = 0; r < 4; ++r) {
          float z = vexp2(c1 * sc[jn][r]);
          float p = vexp2(c2 * z * vrcp(1.f + z));
          if (key > qbase + r) p = 0.f;
          psum[r] += p;
          myP[(4 * g + r) * 72 + jn * 16 + lr] = f2bf(p);
        }
      }
#pragma unroll
      for (int kc = 0; kc < 2; ++kc) {
        bf16x8 pa = *(const bf16x8*)(myP + lr * 72 + kc * 32 + g * 8);
#pragma unroll
        for (int jh = 0; jh < 8; ++jh) {
          int row = jh * 16 + lr;
          int w = (kc * 64 + g * 16) ^ ((row & 7) << 4);
          bf16x8 vf = *(const bf16x8*)((const char*)lsV[cur] + row * 128 + w);
          o[jh] = __builtin_amdgcn_mfma_f32_16x16x32_bf16(pa, vf, o[jh], 0, 0, 0);
        }
      }
      __syncthreads();
      cur ^= 1;
    }
    float lsum[4];
#pragma unroll
    for (int r = 0; r < 4; ++r) {
      float s = psum[r];
#pragma unroll
      for (int msk = 1; msk < 16; msk <<= 1) s += __shfl_xor(s, msk, 64);
      lsum[r] = s;
    }
#pragma unroll
    for (int r = 0; r < 4; ++r) {
      float inv = 1.f / lsum[r];
      int s = qbase + r;
      u16* xp = X + ((size_t)(b * S_ + s)) * D_ + h * HD_;
#pragma unroll
      for (int jh = 0; jh < 8; ++jh) xp[jh * 16 + lr] = f2bf(o[jh][r] * inv);
    }
  }
}

extern "C" void kernel_launch(void* const* d_in, const int* in_sizes, int n_in,
                              void* d_out, int out_size, void* d_ws, size_t ws_size,
                              hipStream_t stream) {
  const float* inputs = (const float*)d_in[0];
  const float* w_in = (const float*)d_in[1];
  const float* w_out = (const float*)d_in[2];
  const float* rsin = (const float*)d_in[3];
  const float* rcos = (const float*)d_in[4];
  float* out = (float*)d_out;

  char* ws = (char*)d_ws;
  u16* bfA = (u16*)(ws);                // (B*S, D) bf16
  u16* w_inT = (u16*)(ws + 16777216);   // (6144, 2048) bf16, sigma-permuted
  u16* Qraw = (u16*)(ws + 41943040);    // (B,H,S,HD) roped, Q pre-scaled
  u16* Kraw = (u16*)(ws + 58720256);    // (B,H,S,HD) roped
  u16* VT = (u16*)(ws + 75497472);      // (B,H,HD,S)
  u16* Xbuf = (u16*)(ws);               // reuse bfA region
  u16* w_outT = (u16*)(ws + 16777216);  // reuse w_inT region

  conv_f32_bf16<<<2048, 256, 0, stream>>>(inputs, bfA, B_ * S_ * D_);
  transpose_win<<<dim3(192, 64), 256, 0, stream>>>(w_in, w_inT);
  gemm256_8p<1><<<384, 512, 0, stream>>>(bfA, w_inT, nullptr, 2048, 6144, 24, Qraw, Kraw, VT,
                                         rsin, rcos);
  transpose_conv<<<dim3(64, 64), 256, 0, stream>>>(w_out, w_outT, 2048, 2048);
  attn_fwd<<<dim3(NT_ / 2, 32), 256, 0, stream>>>(Qraw, Kraw, VT, Xbuf);
  gemm8p<0><<<256, 512, 0, stream>>>(Xbuf, w_outT, out, 2048, 2048, 16,
                                     nullptr, nullptr, nullptr);
}